// Round 20
// baseline (388.805 us; speedup 1.0000x reference)
//
#include <hip/hip_runtime.h>
#include <math.h>

#define NN   100000
#define NE   1600000
#define DIN  128
#define HID  256
#define NG   64
#define NCLS 10

// counting-sort CSR build parameters
#define NBLK 128          // edge-chunk blocks (NE/NBLK = 12500 exactly)
#define EPB  (NE / NBLK)
#define NBUK 512          // dst buckets
#define NPB  196          // nodes per bucket (512*196 = 100352 >= NN)
#define NHIST (NBUK * NBLK)   // 65536 = 64 chunks x 1024
#define NBR  ((NN + 127) / 128)   // row-blocks, GEMM1 grid (782)
#define NBR2 ((NN + 63) / 64)     // row-blocks, fused layer-2 grid (1563)

using bf16x8 = __attribute__((ext_vector_type(8))) short;
using f32x4  = __attribute__((ext_vector_type(4))) float;
using f32x2  = __attribute__((ext_vector_type(2))) float;
using u32x2  = __attribute__((ext_vector_type(2))) unsigned int;
using u32x4  = __attribute__((ext_vector_type(4))) unsigned int;

static __device__ __forceinline__ unsigned short f2bf(float f) {
    unsigned u = __float_as_uint(f);
    u += 0x7fff + ((u >> 16) & 1);   // round-to-nearest-even
    return (unsigned short)(u >> 16);
}

// ---- OCP fp8 e4m3 helpers ----
static __device__ __forceinline__ unsigned char f32_to_fp8(float f) {
    float a = fminf(fabsf(f), 448.f);
    unsigned bits = __float_as_uint(a * 0x1p-120f);
    bits += 0x7ffff + ((bits >> 20) & 1);
    unsigned e4 = (bits >> 20) & 0x7f;
    return (unsigned char)(e4 | (f < 0.f ? 0x80u : 0u));
}
#if __has_builtin(__builtin_amdgcn_cvt_pk_f32_fp8)
#define HAVE_CVT_FP8 1
#endif
static __device__ __forceinline__ void fp8x4_to_f32(unsigned u, float* f) {
#ifdef HAVE_CVT_FP8
    f32x2 lo = __builtin_amdgcn_cvt_pk_f32_fp8((int)u, false);
    f32x2 hi = __builtin_amdgcn_cvt_pk_f32_fp8((int)u, true);
    f[0] = lo[0]; f[1] = lo[1]; f[2] = hi[0]; f[3] = hi[1];
#else
#pragma unroll
    for (int k = 0; k < 4; ++k) {
        unsigned b = (u >> (8 * k)) & 0xffu;
        unsigned bits = ((b & 0x80u) << 24) | ((b & 0x7fu) << 20);
        f[k] = __uint_as_float(bits) * 0x1p+120f;
    }
#endif
}
// 8 fp8 -> 8 bf16 packed (exact: e4m3 values are bf16-representable)
static __device__ __forceinline__ int4 fp8x8_to_bf16x8(unsigned lo, unsigned hi) {
    float f[8];
    fp8x4_to_f32(lo, f);
    fp8x4_to_f32(hi, f + 4);
    int4 r;
    r.x = (int)((__float_as_uint(f[0]) >> 16) | (__float_as_uint(f[1]) & 0xffff0000u));
    r.y = (int)((__float_as_uint(f[2]) >> 16) | (__float_as_uint(f[3]) & 0xffff0000u));
    r.z = (int)((__float_as_uint(f[4]) >> 16) | (__float_as_uint(f[5]) & 0xffff0000u));
    r.w = (int)((__float_as_uint(f[6]) >> 16) | (__float_as_uint(f[7]) & 0xffff0000u));
    return r;
}

// ---------------- graph preprocessing: bucketed counting sort ----------------

__global__ __launch_bounds__(256) void k_hist(const int* __restrict__ dst,
                                              int* __restrict__ histg) {
    __shared__ int h[NBUK];
    const int t = threadIdx.x;
    for (int i = t; i < NBUK; i += 256) h[i] = 0;
    __syncthreads();
    const int e0 = blockIdx.x * EPB, e1 = e0 + EPB;
    for (int e = e0 + t; e < e1; e += 256)
        atomicAdd(&h[(unsigned)__builtin_nontemporal_load(&dst[e]) / NPB], 1);
    __syncthreads();
    for (int i = t; i < NBUK; i += 256)
        histg[i * NBLK + blockIdx.x] = h[i];
}

__global__ __launch_bounds__(256) void k_bsum2(const int* __restrict__ d,
                                               int* __restrict__ bsum) {
    __shared__ int sd[256];
    int t = threadIdx.x;
    const int4 v = *(const int4*)&d[blockIdx.x * 1024 + t * 4];
    sd[t] = v.x + v.y + v.z + v.w;
    __syncthreads();
    for (int off = 128; off > 0; off >>= 1) {
        if (t < off) sd[t] += sd[t + off];
        __syncthreads();
    }
    if (t == 0) bsum[blockIdx.x] = sd[0];
}

__global__ void k_scanb2(const int* __restrict__ bsum, int* __restrict__ boff,
                         const int* __restrict__ batch, float* __restrict__ countsf) {
    __shared__ int tmp[64];
    int t = threadIdx.x;
    int v = bsum[t];
    tmp[t] = v; __syncthreads();
    for (int off = 1; off < 64; off <<= 1) {
        int u = (t >= off) ? tmp[t - off] : 0;
        __syncthreads();
        tmp[t] += u;
        __syncthreads();
    }
    boff[t] = tmp[t] - v;
    int g = t;
    int lo = 0, hi = NN;
    while (lo < hi) { int mid = (lo + hi) >> 1; if (batch[mid] < g) lo = mid + 1; else hi = mid; }
    int lb = lo;
    lo = 0; hi = NN;
    while (lo < hi) { int mid = (lo + hi) >> 1; if (batch[mid] <= g) lo = mid + 1; else hi = mid; }
    countsf[g] = (float)(lo - lb);
}

__global__ __launch_bounds__(256) void k_offs2(int* __restrict__ d,
                                               const int* __restrict__ boff) {
    __shared__ int ts[256];
    int t = threadIdx.x;
    int base = blockIdx.x * 1024 + t * 4;
    int4 v = *(const int4*)&d[base];
    int s = v.x + v.y + v.z + v.w;
    ts[t] = s; __syncthreads();
    for (int off = 1; off < 256; off <<= 1) {
        int u = (t >= off) ? ts[t - off] : 0;
        __syncthreads();
        ts[t] += u;
        __syncthreads();
    }
    int run = ts[t] - s + boff[blockIdx.x];
    int4 o;
    o.x = run; run += v.x;
    o.y = run; run += v.y;
    o.z = run; run += v.z;
    o.w = run; run += v.w;
    *(int4*)&d[base] = o;
}

__global__ __launch_bounds__(256) void k_scatter(const int* __restrict__ src,
                                                 const int* __restrict__ dst,
                                                 const int* __restrict__ offg,
                                                 unsigned* __restrict__ pairs) {
    __shared__ int cur[NBUK];
    const int t = threadIdx.x;
    for (int i = t; i < NBUK; i += 256) cur[i] = offg[i * NBLK + blockIdx.x];
    __syncthreads();
    const int e0 = blockIdx.x * EPB, e1 = e0 + EPB;
    for (int e = e0 + t; e < e1; e += 256) {
        int d = __builtin_nontemporal_load(&dst[e]);
        int sv = __builtin_nontemporal_load(&src[e]);
        int b = (unsigned)d / NPB;
        int li = d - b * NPB;
        unsigned pk = ((unsigned)li << 24) | (unsigned)sv;
        int p = atomicAdd(&cur[b], 1);
        __builtin_nontemporal_store(pk, &pairs[p]);
    }
}

__global__ __launch_bounds__(256) void k_csr(const unsigned* __restrict__ pairs,
                                             const int* __restrict__ offg,
                                             int* __restrict__ csr,
                                             int* __restrict__ deg,
                                             float* __restrict__ dinv,
                                             int* __restrict__ offs) {
    __shared__ int cnt[NPB];
    __shared__ int loff[256];
    __shared__ int cur[NPB];
    const int b = blockIdx.x, t = threadIdx.x;
    const int s     = offg[b * NBLK];
    const int e_end = (b == NBUK - 1) ? NE : offg[(b + 1) * NBLK];
    const int nb0   = b * NPB;
    const int nnod  = min(NPB, NN - nb0);
    if (t < NPB) cnt[t] = 0;
    __syncthreads();
    for (int e = s + t; e < e_end; e += 256)
        atomicAdd(&cnt[pairs[e] >> 24], 1);
    __syncthreads();
    int v = (t < NPB) ? cnt[t] : 0;
    loff[t] = v;
    __syncthreads();
    for (int off = 1; off < 256; off <<= 1) {
        int u = (t >= off) ? loff[t - off] : 0;
        __syncthreads();
        loff[t] += u;
        __syncthreads();
    }
    int myoff = loff[t] - v;
    __syncthreads();
    loff[t] = myoff;
    if (t < NPB) cur[t] = 0;
    __syncthreads();
    if (t < nnod) {
        int node = nb0 + t;
        int dg = cnt[t];
        deg[node]  = dg;
        dinv[node] = rsqrtf((float)(dg + 1));
        offs[node] = s + myoff;
    }
    for (int e = s + t; e < e_end; e += 256) {
        unsigned pk = pairs[e];
        int li = pk >> 24;
        int p = atomicAdd(&cur[li], 1);
        csr[s + loff[li] + p] = (int)(pk & 0xffffffu);
    }
}

// ---------------- merged casts ----------------

#define XQ (NN * 32)   // x quads

__global__ void k_cast_all(const float* __restrict__ x, const float* __restrict__ dinv,
                           unsigned char* __restrict__ xs8,
                           const float* __restrict__ W1, unsigned short* __restrict__ Wt1,
                           const float* __restrict__ W2, unsigned short* __restrict__ Wt2) {
    int i = blockIdx.x * blockDim.x + threadIdx.x;
    if (i < XQ) {
        int nd = i >> 5;
        int q  = i & 31;
        float dv = dinv[nd];
        const float4 v = *(const float4*)&x[(size_t)nd * DIN + q * 4];
        uchar4 o;
        o.x = f32_to_fp8(v.x * dv); o.y = f32_to_fp8(v.y * dv);
        o.z = f32_to_fp8(v.z * dv); o.w = f32_to_fp8(v.w * dv);
        *(uchar4*)&xs8[(size_t)nd * DIN + q * 4] = o;
        return;
    }
    int j = i - XQ;
    if (j < DIN * HID) {
        int k = j >> 8, nc = j & 255;
        Wt1[nc * DIN + k] = f2bf(W1[j]);
    } else if (j < (DIN + HID) * HID) {
        int jj = j - DIN * HID;
        int k = jj >> 8, nc = jj & 255;
        Wt2[nc * HID + k] = f2bf(W2[jj]);
    }
}

// ---------------- GEMM1: 128 rows x 256 cols per block, 8 waves, BK=64 (unchanged) ------
// out_fp8[row*HID+col] = e4m3(dinv[row] * relu(acc + bias[col]))

__global__ __launch_bounds__(512) void k_gemm1(const unsigned char* __restrict__ A8,
                                               const unsigned short* __restrict__ Wt,
                                               const float* __restrict__ dinv,
                                               const float* __restrict__ bias,
                                               unsigned char* __restrict__ out8,
                                               int M, int K) {
    __shared__ unsigned short As[128 * 72];
    __shared__ unsigned short Bs[256 * 72];
    const int t = threadIdx.x;
    const int lane = t & 63;
    const int wid = t >> 6;
    const int wr = wid & 1, wc = wid >> 1;
    const int bm = blockIdx.x * 128;
    const int lr = lane & 15;
    const int ko = (lane >> 4) << 3;

    f32x4 acc[4][4] = {};

    const int arow = t >> 2;
    const int akq  = (t & 3) << 4;
    const int brow = t >> 1;
    const int bkq  = (t & 1) << 5;

    for (int kk = 0; kk < K; kk += 64) {
        {
            int row = bm + arow;
            u32x4 v; v.x = v.y = v.z = v.w = 0u;
            if (row < M) v = *(const u32x4*)&A8[(size_t)row * K + kk + akq];
            *(int4*)&As[arow * 72 + akq]     = fp8x8_to_bf16x8(v.x, v.y);
            *(int4*)&As[arow * 72 + akq + 8] = fp8x8_to_bf16x8(v.z, v.w);
        }
        {
            const unsigned short* wsrc = &Wt[(size_t)brow * K + kk + bkq];
#pragma unroll
            for (int q = 0; q < 4; ++q)
                *(int4*)&Bs[brow * 72 + bkq + q * 8] = *(const int4*)&wsrc[q * 8];
        }
        __syncthreads();
#pragma unroll
        for (int ks = 0; ks < 64; ks += 32) {
            bf16x8 af[4], bfr[4];
#pragma unroll
            for (int mf = 0; mf < 4; ++mf)
                af[mf] = *(const bf16x8*)&As[(wr * 64 + mf * 16 + lr) * 72 + ks + ko];
#pragma unroll
            for (int nf = 0; nf < 4; ++nf)
                bfr[nf] = *(const bf16x8*)&Bs[(wc * 64 + nf * 16 + lr) * 72 + ks + ko];
#pragma unroll
            for (int mf = 0; mf < 4; ++mf)
#pragma unroll
                for (int nf = 0; nf < 4; ++nf)
                    acc[mf][nf] = __builtin_amdgcn_mfma_f32_16x16x32_bf16(af[mf], bfr[nf], acc[mf][nf], 0, 0, 0);
        }
        __syncthreads();
    }

#pragma unroll
    for (int mf = 0; mf < 4; ++mf) {
#pragma unroll
        for (int b = 0; b < 4; ++b) {
            int row = bm + wr * 64 + mf * 16 + (lane >> 4) * 4 + b;
            if (row >= M) continue;
            float dv = dinv[row];
#pragma unroll
            for (int nf = 0; nf < 4; ++nf) {
                int col = wc * 64 + nf * 16 + lr;
                float v = fmaxf(acc[mf][nf][b] + bias[col], 0.f);
                out8[(size_t)row * HID + col] = f32_to_fp8(dv * v);
            }
        }
    }
}

// ---------------- FUSED layer 2: gather(h8) -> GEMM(wt2) -> pooled psum -> scratch --------
// Block = 64 rows x 256 cols, 512 threads (8 waves). Phase 1: wave-per-node gather of the
// block's 64 nodes into bf16 As (full K=256). Phase 2: BK=64 GEMM, wave tile 32x64.
// 2 blocks/CU (LDS ~75KB): block A's MFMA overlaps block B's gather on the same CU.

__global__ __launch_bounds__(512) void k_agg_gemm2(const unsigned char* __restrict__ h8,
                                                   const int* __restrict__ csr,
                                                   const int* __restrict__ offs,
                                                   const int* __restrict__ deg,
                                                   const float* __restrict__ dinv,
                                                   const unsigned short* __restrict__ Wt,
                                                   const float* __restrict__ bias,
                                                   float* __restrict__ scratch,
                                                   const int* __restrict__ batch,
                                                   int M) {
    __shared__ unsigned short As[64 * 264];   // full K=256 + 8 pad (stride 528B: 2-way bank alias, free)
    __shared__ unsigned short Bs[256 * 72];
    __shared__ float psum[4][256];
    __shared__ int gloc[64];
    const int t = threadIdx.x;
    const int lane = t & 63;
    const int wv = t >> 6;                    // 0..7
    const int bm = blockIdx.x * 64;
    const int lr = lane & 15;
    const int ko = (lane >> 4) << 3;

    const int g0 = batch[bm];
    const int gend = batch[min(bm + 63, M - 1)];
    for (int i = t; i < 4 * 256; i += 512) ((float*)psum)[i] = 0.f;
    if (t < 64) gloc[t] = (bm + t < M) ? min(batch[bm + t] - g0, 3) : 0;

    // ---- phase 1: gather (wave per node, 8 nodes per wave serially) ----
    const int c = lane << 2;                  // channel base
    for (int ni = wv; ni < 64; ni += 8) {
        int node = bm + ni;
        float a0 = 0.f, a1 = 0.f, a2 = 0.f, a3 = 0.f;
        if (node < M) {
            unsigned u = *(const unsigned*)&h8[(size_t)node * HID + c];
            float f[4]; fp8x4_to_f32(u, f);
            a0 = f[0]; a1 = f[1]; a2 = f[2]; a3 = f[3];
            int s0 = offs[node], cnt = deg[node];
            for (int base = 0; base < cnt; base += 64) {
                int nb = min(64, cnt - base);
                int idx = (lane < nb) ? __builtin_nontemporal_load(&csr[s0 + base + lane]) : 0;
                int i = 0;
                for (; i + 8 <= nb; i += 8) {
                    unsigned v[8];
#pragma unroll
                    for (int k = 0; k < 8; ++k) {
                        int j = __shfl(idx, i + k);
                        v[k] = *(const unsigned*)&h8[(size_t)j * HID + c];
                    }
#pragma unroll
                    for (int k = 0; k < 8; ++k) {
                        float f2[4]; fp8x4_to_f32(v[k], f2);
                        a0 += f2[0]; a1 += f2[1]; a2 += f2[2]; a3 += f2[3];
                    }
                }
                for (; i < nb; ++i) {
                    int j = __shfl(idx, i);
                    unsigned uu = *(const unsigned*)&h8[(size_t)j * HID + c];
                    float f2[4]; fp8x4_to_f32(uu, f2);
                    a0 += f2[0]; a1 += f2[1]; a2 += f2[2]; a3 += f2[3];
                }
            }
            float dv = dinv[node];
            a0 *= dv; a1 *= dv; a2 *= dv; a3 *= dv;
        }
        ushort4 w;
        w.x = f2bf(a0); w.y = f2bf(a1); w.z = f2bf(a2); w.w = f2bf(a3);
        *(ushort4*)&As[ni * 264 + c] = w;
    }
    __syncthreads();

    // ---- phase 2: GEMM, wave tile 32x64 (wr in {0,1}, wc in {0..3}) ----
    const int wr = wv & 1, wc = wv >> 1;
    f32x4 acc[2][4] = {};
    const int brow = t >> 1;
    const int bkq  = (t & 1) << 5;

    for (int kk = 0; kk < HID; kk += 64) {
        const unsigned short* wsrc = &Wt[(size_t)brow * HID + kk + bkq];
#pragma unroll
        for (int q = 0; q < 4; ++q)
            *(int4*)&Bs[brow * 72 + bkq + q * 8] = *(const int4*)&wsrc[q * 8];
        __syncthreads();
#pragma unroll
        for (int ks = 0; ks < 64; ks += 32) {
            bf16x8 af[2], bfr[4];
#pragma unroll
            for (int mf = 0; mf < 2; ++mf)
                af[mf] = *(const bf16x8*)&As[(wr * 32 + mf * 16 + lr) * 264 + kk + ks + ko];
#pragma unroll
            for (int nf = 0; nf < 4; ++nf)
                bfr[nf] = *(const bf16x8*)&Bs[(wc * 64 + nf * 16 + lr) * 72 + ks + ko];
#pragma unroll
            for (int mf = 0; mf < 2; ++mf)
#pragma unroll
                for (int nf = 0; nf < 4; ++nf)
                    acc[mf][nf] = __builtin_amdgcn_mfma_f32_16x16x32_bf16(af[mf], bfr[nf], acc[mf][nf], 0, 0, 0);
        }
        __syncthreads();
    }

    // ---- epilogue: relu+bias, pooled partial sums ----
    const int q4 = (lane >> 4) << 2;
    if (gend == g0) {
#pragma unroll
        for (int nf = 0; nf < 4; ++nf) {
            const int lcol = wc * 64 + nf * 16 + lr;
            const float bb = bias[lcol];
            float rsum = 0.f;
#pragma unroll
            for (int mf = 0; mf < 2; ++mf)
#pragma unroll
                for (int b = 0; b < 4; ++b) {
                    int lrow = wr * 32 + mf * 16 + q4 + b;
                    if (bm + lrow < M) rsum += fmaxf(acc[mf][nf][b] + bb, 0.f);
                }
            rsum += __shfl_xor(rsum, 16);
            rsum += __shfl_xor(rsum, 32);
            if ((lane >> 4) == 0) atomicAdd(&psum[0][lcol], rsum);
        }
    } else {
#pragma unroll
        for (int nf = 0; nf < 4; ++nf) {
            const int lcol = wc * 64 + nf * 16 + lr;
            const float bb = bias[lcol];
            float run = 0.f; int gcur = 0;
#pragma unroll
            for (int mf = 0; mf < 2; ++mf) {
#pragma unroll
                for (int b = 0; b < 4; ++b) {
                    int lrow = wr * 32 + mf * 16 + q4 + b;
                    if (bm + lrow < M) {
                        int gl = gloc[lrow];
                        float v = fmaxf(acc[mf][nf][b] + bb, 0.f);
                        if (gl != gcur) {
                            if (run != 0.f) atomicAdd(&psum[gcur][lcol], run);
                            run = 0.f; gcur = gl;
                        }
                        run += v;
                    }
                }
            }
            if (run != 0.f) atomicAdd(&psum[gcur][lcol], run);
        }
    }
    __syncthreads();
    size_t base = (size_t)blockIdx.x * 1024;
    for (int i = t; i < 1024; i += 512)
        __builtin_nontemporal_store(((const float*)psum)[i], &scratch[base + i]);
}

// ---------------- aggregation, 128 channels, fp8 gather, fp8 output (layer 1) -------------

__global__ __launch_bounds__(256) void k_agg128(const unsigned char* __restrict__ xs,
                                                const int* __restrict__ csr,
                                                const int* __restrict__ offs,
                                                const int* __restrict__ deg,
                                                const float* __restrict__ dinv,
                                                unsigned char* __restrict__ out, int n) {
    int wid = threadIdx.x >> 6, lane = threadIdx.x & 63;
    int node = blockIdx.x * 4 + wid;
    if (node >= n) return;
    int half = lane >> 5, l32 = lane & 31;
    int c = l32 << 2;
    float a0 = 0.f, a1 = 0.f, a2 = 0.f, a3 = 0.f;
    if (half == 0) {
        unsigned u = *(const unsigned*)&xs[(size_t)node * DIN + c];
        float f[4]; fp8x4_to_f32(u, f);
        a0 = f[0]; a1 = f[1]; a2 = f[2]; a3 = f[3];
    }
    int s0 = offs[node], cnt = deg[node];
    for (int base = 0; base < cnt; base += 64) {
        int nb = min(64, cnt - base);
        int idx = (lane < nb) ? __builtin_nontemporal_load(&csr[s0 + base + lane]) : 0;
        int i = 0;
        for (; i + 8 <= nb; i += 8) {
            unsigned v[4];
#pragma unroll
            for (int k = 0; k < 4; ++k) {
                int j = __shfl(idx, i + 2 * k + half);
                v[k] = *(const unsigned*)&xs[(size_t)j * DIN + c];
            }
#pragma unroll
            for (int k = 0; k < 4; ++k) {
                float f[4]; fp8x4_to_f32(v[k], f);
                a0 += f[0]; a1 += f[1]; a2 += f[2]; a3 += f[3];
            }
        }
        for (; i < nb; i += 2) {
            int e = i + half;
            int j = __shfl(idx, e < nb ? e : 0);
            if (e < nb) {
                unsigned u = *(const unsigned*)&xs[(size_t)j * DIN + c];
                float f[4]; fp8x4_to_f32(u, f);
                a0 += f[0]; a1 += f[1]; a2 += f[2]; a3 += f[3];
            }
        }
    }
    a0 += __shfl_xor(a0, 32);
    a1 += __shfl_xor(a1, 32);
    a2 += __shfl_xor(a2, 32);
    a3 += __shfl_xor(a3, 32);
    if (half == 0) {
        float dv = dinv[node];
        uchar4 r;
        r.x = f32_to_fp8(dv * a0); r.y = f32_to_fp8(dv * a1);
        r.z = f32_to_fp8(dv * a2); r.w = f32_to_fp8(dv * a3);
        *(uchar4*)&out[(size_t)node * DIN + c] = r;
    }
}

// ---------------- head MLP with fused pooled-reduction from scratch ----------------

__global__ __launch_bounds__(256) void k_mlp(const float* __restrict__ scratch,
                                             const int* __restrict__ batch,
                                             const float* __restrict__ countsf,
                                             const float* __restrict__ Wf1,
                                             const float* __restrict__ bf1,
                                             const float* __restrict__ Wf2,
                                             const float* __restrict__ bf2,
                                             float* __restrict__ out) {
    __shared__ float p[HID];
    __shared__ float z[HID];
    int g = blockIdx.x, t = threadIdx.x;
    // node range of graph g
    int lo = 0, hi = NN;
    while (lo < hi) { int mid = (lo + hi) >> 1; if (batch[mid] < g) lo = mid + 1; else hi = mid; }
    int s = lo;
    lo = s; hi = NN;
    while (lo < hi) { int mid = (lo + hi) >> 1; if (batch[mid] <= g) lo = mid + 1; else hi = mid; }
    int e = lo;
    float sum = 0.f;
    if (e > s) {
        int bx0 = s >> 6, bx1 = (e - 1) >> 6;
        for (int bx = bx0; bx <= bx1; ++bx) {
            int gl = min(g - batch[bx << 6], 3);
            sum += scratch[(size_t)bx * 1024 + gl * 256 + t];
        }
    }
    float cnt = fmaxf(countsf[g], 1.0f);
    p[t] = sum / cnt;
    __syncthreads();
    float accz = bf1[t];
    for (int k = 0; k < HID; ++k)
        accz = fmaf(p[k], Wf1[k * HID + t], accz);
    z[t] = fmaxf(accz, 0.f);
    __syncthreads();
    if (t < NCLS) {
        float o = bf2[t];
        for (int k = 0; k < HID; ++k)
            o = fmaf(z[k], Wf2[k * NCLS + t], o);
        float sp = fmaxf(o, 0.f) + log1pf(expf(-fabsf(o)));
        out[g * NCLS + t] = sp + 0.001f;
    }
}

// ---------------- launch ----------------

extern "C" void kernel_launch(void* const* d_in, const int* in_sizes, int n_in,
                              void* d_out, int out_size, void* d_ws, size_t ws_size,
                              hipStream_t stream) {
    const float* x     = (const float*)d_in[0];
    const int*   ei    = (const int*)d_in[1];
    const int*   batch = (const int*)d_in[2];
    const float* W1    = (const float*)d_in[3];
    const float* b1    = (const float*)d_in[4];
    const float* W2    = (const float*)d_in[5];
    const float* b2    = (const float*)d_in[6];
    const float* Wf1   = (const float*)d_in[7];
    const float* bf1   = (const float*)d_in[8];
    const float* Wf2   = (const float*)d_in[9];
    const float* bf2   = (const float*)d_in[10];
    float* out = (float*)d_out;

    const int* srcv = ei;
    const int* dstv = ei + NE;

    char* p = (char*)d_ws;
    auto take = [&](size_t bytes) -> char* {
        char* q = p; p += (bytes + 255) & ~(size_t)255; return q;
    };
    // big0 (51.2MB): [xs8 fp8 12.8MB][xa8 fp8 12.8MB]
    char* big0 = take((size_t)NN * HID * 2);
    // big1 (51.2MB): pairs u32 (6.4MB) early; h8 fp8 (25.6MB) + scratch (6.4MB) later
    char* big1 = take((size_t)NN * HID * 2);
    unsigned char*  xs8 = (unsigned char*)big0;                            // [NN][128] fp8
    unsigned char*  xa8 = (unsigned char*)(big0 + (size_t)NN * DIN);       // [NN][128] fp8
    unsigned char*  h8  = (unsigned char*)big1;                            // [NN][256] fp8
    float* scratch = (float*)(big1 + (size_t)NN * HID);                    // [NBR2][4][256] f32
    unsigned* pairs = (unsigned*)big1;                                     // dead before h8
    unsigned short* wt1  = (unsigned short*)take((size_t)DIN * HID * 2);
    unsigned short* wt2  = (unsigned short*)take((size_t)HID * HID * 2);
    int*   histg   = (int*)take((size_t)NHIST * 4);
    int*   bsum    = (int*)take(64 * 4);
    int*   boff    = (int*)take(64 * 4);
    int*   deg     = (int*)take((size_t)NN * 4);
    int*   offs    = (int*)take((size_t)NN * 4);
    int*   csr     = (int*)take((size_t)NE * 4);
    float* dinv    = (float*)take((size_t)NN * 4);
    float* countsf = (float*)take((size_t)NG * 4);

    k_hist<<<NBLK, 256, 0, stream>>>(dstv, histg);
    k_bsum2<<<64, 256, 0, stream>>>(histg, bsum);
    k_scanb2<<<1, 64, 0, stream>>>(bsum, boff, batch, countsf);
    k_offs2<<<64, 256, 0, stream>>>(histg, boff);
    k_scatter<<<NBLK, 256, 0, stream>>>(srcv, dstv, histg, pairs);
    k_csr<<<NBUK, 256, 0, stream>>>(pairs, histg, csr, deg, dinv, offs);

    int cast_total = XQ + (DIN + HID) * HID;
    k_cast_all<<<(cast_total + 255) / 256, 256, 0, stream>>>(x, dinv, xs8, W1, wt1, W2, wt2);

    // layer 1: fp8 gather -> xa8, GEMM1 (writes h8 fp8)
    k_agg128<<<(NN + 3) / 4, 256, 0, stream>>>(xs8, csr, offs, deg, dinv, xa8, NN);
    k_gemm1<<<NBR, 512, 0, stream>>>(xa8, wt1, dinv, b1, h8, NN, DIN);
    // layer 2: FUSED gather + GEMM2 + pooling partials
    k_agg_gemm2<<<NBR2, 512, 0, stream>>>(h8, csr, offs, deg, dinv, wt2, b2,
                                          scratch, batch, NN);
    // head: fused reduce + MLP
    k_mlp<<<NG, 256, 0, stream>>>(scratch, batch, countsf, Wf1, bf1, Wf2, bf2, out);
}

// Round 21
// 324.402 us; speedup vs baseline: 1.1985x; 1.1985x over previous
//
#include <hip/hip_runtime.h>
#include <math.h>

#define NN   100000
#define NE   1600000
#define DIN  128
#define HID  256
#define NG   64
#define NCLS 10

// counting-sort CSR build parameters
#define NBLK 128          // edge-chunk blocks (NE/NBLK = 12500 exactly)
#define EPB  (NE / NBLK)
#define NBUK 512          // dst buckets
#define NPB  196          // nodes per bucket (512*196 = 100352 >= NN)
#define NHIST (NBUK * NBLK)   // 65536 = 64 chunks x 1024
#define NBR  ((NN + 127) / 128)   // 782 row-blocks in the GEMM grid

using bf16x8 = __attribute__((ext_vector_type(8))) short;
using f32x4  = __attribute__((ext_vector_type(4))) float;
using f32x2  = __attribute__((ext_vector_type(2))) float;
using u32x2  = __attribute__((ext_vector_type(2))) unsigned int;
using u32x4  = __attribute__((ext_vector_type(4))) unsigned int;

static __device__ __forceinline__ unsigned short f2bf(float f) {
    unsigned u = __float_as_uint(f);
    u += 0x7fff + ((u >> 16) & 1);   // round-to-nearest-even
    return (unsigned short)(u >> 16);
}

// ---- OCP fp8 e4m3 helpers ----
static __device__ __forceinline__ unsigned char f32_to_fp8(float f) {
    float a = fminf(fabsf(f), 448.f);
    unsigned bits = __float_as_uint(a * 0x1p-120f);
    bits += 0x7ffff + ((bits >> 20) & 1);
    unsigned e4 = (bits >> 20) & 0x7f;
    return (unsigned char)(e4 | (f < 0.f ? 0x80u : 0u));
}
#if __has_builtin(__builtin_amdgcn_cvt_pk_f32_fp8)
#define HAVE_CVT_FP8 1
#endif
static __device__ __forceinline__ void fp8x4_to_f32(unsigned u, float* f) {
#ifdef HAVE_CVT_FP8
    f32x2 lo = __builtin_amdgcn_cvt_pk_f32_fp8((int)u, false);
    f32x2 hi = __builtin_amdgcn_cvt_pk_f32_fp8((int)u, true);
    f[0] = lo[0]; f[1] = lo[1]; f[2] = hi[0]; f[3] = hi[1];
#else
#pragma unroll
    for (int k = 0; k < 4; ++k) {
        unsigned b = (u >> (8 * k)) & 0xffu;
        unsigned bits = ((b & 0x80u) << 24) | ((b & 0x7fu) << 20);
        f[k] = __uint_as_float(bits) * 0x1p+120f;
    }
#endif
}
// 8 fp8 -> 8 bf16 packed (exact: e4m3 values are bf16-representable)
static __device__ __forceinline__ int4 fp8x8_to_bf16x8(unsigned lo, unsigned hi) {
    float f[8];
    fp8x4_to_f32(lo, f);
    fp8x4_to_f32(hi, f + 4);
    int4 r;
    r.x = (int)((__float_as_uint(f[0]) >> 16) | (__float_as_uint(f[1]) & 0xffff0000u));
    r.y = (int)((__float_as_uint(f[2]) >> 16) | (__float_as_uint(f[3]) & 0xffff0000u));
    r.z = (int)((__float_as_uint(f[4]) >> 16) | (__float_as_uint(f[5]) & 0xffff0000u));
    r.w = (int)((__float_as_uint(f[6]) >> 16) | (__float_as_uint(f[7]) & 0xffff0000u));
    return r;
}

// ---------------- graph preprocessing: bucketed counting sort ----------------

__global__ __launch_bounds__(256) void k_hist(const int* __restrict__ dst,
                                              int* __restrict__ histg) {
    __shared__ int h[NBUK];
    const int t = threadIdx.x;
    for (int i = t; i < NBUK; i += 256) h[i] = 0;
    __syncthreads();
    const int e0 = blockIdx.x * EPB, e1 = e0 + EPB;
    for (int e = e0 + t; e < e1; e += 256)
        atomicAdd(&h[(unsigned)__builtin_nontemporal_load(&dst[e]) / NPB], 1);
    __syncthreads();
    for (int i = t; i < NBUK; i += 256)
        histg[i * NBLK + blockIdx.x] = h[i];
}

__global__ __launch_bounds__(256) void k_bsum2(const int* __restrict__ d,
                                               int* __restrict__ bsum) {
    __shared__ int sd[256];
    int t = threadIdx.x;
    const int4 v = *(const int4*)&d[blockIdx.x * 1024 + t * 4];
    sd[t] = v.x + v.y + v.z + v.w;
    __syncthreads();
    for (int off = 128; off > 0; off >>= 1) {
        if (t < off) sd[t] += sd[t + off];
        __syncthreads();
    }
    if (t == 0) bsum[blockIdx.x] = sd[0];
}

__global__ void k_scanb2(const int* __restrict__ bsum, int* __restrict__ boff,
                         const int* __restrict__ batch, float* __restrict__ countsf) {
    __shared__ int tmp[64];
    int t = threadIdx.x;
    int v = bsum[t];
    tmp[t] = v; __syncthreads();
    for (int off = 1; off < 64; off <<= 1) {
        int u = (t >= off) ? tmp[t - off] : 0;
        __syncthreads();
        tmp[t] += u;
        __syncthreads();
    }
    boff[t] = tmp[t] - v;
    int g = t;
    int lo = 0, hi = NN;
    while (lo < hi) { int mid = (lo + hi) >> 1; if (batch[mid] < g) lo = mid + 1; else hi = mid; }
    int lb = lo;
    lo = 0; hi = NN;
    while (lo < hi) { int mid = (lo + hi) >> 1; if (batch[mid] <= g) lo = mid + 1; else hi = mid; }
    countsf[g] = (float)(lo - lb);
}

__global__ __launch_bounds__(256) void k_offs2(int* __restrict__ d,
                                               const int* __restrict__ boff) {
    __shared__ int ts[256];
    int t = threadIdx.x;
    int base = blockIdx.x * 1024 + t * 4;
    int4 v = *(const int4*)&d[base];
    int s = v.x + v.y + v.z + v.w;
    ts[t] = s; __syncthreads();
    for (int off = 1; off < 256; off <<= 1) {
        int u = (t >= off) ? ts[t - off] : 0;
        __syncthreads();
        ts[t] += u;
        __syncthreads();
    }
    int run = ts[t] - s + boff[blockIdx.x];
    int4 o;
    o.x = run; run += v.x;
    o.y = run; run += v.y;
    o.z = run; run += v.z;
    o.w = run; run += v.w;
    *(int4*)&d[base] = o;
}

__global__ __launch_bounds__(256) void k_scatter(const int* __restrict__ src,
                                                 const int* __restrict__ dst,
                                                 const int* __restrict__ offg,
                                                 unsigned* __restrict__ pairs) {
    __shared__ int cur[NBUK];
    const int t = threadIdx.x;
    for (int i = t; i < NBUK; i += 256) cur[i] = offg[i * NBLK + blockIdx.x];
    __syncthreads();
    const int e0 = blockIdx.x * EPB, e1 = e0 + EPB;
    for (int e = e0 + t; e < e1; e += 256) {
        int d = __builtin_nontemporal_load(&dst[e]);
        int sv = __builtin_nontemporal_load(&src[e]);
        int b = (unsigned)d / NPB;
        int li = d - b * NPB;
        unsigned pk = ((unsigned)li << 24) | (unsigned)sv;
        int p = atomicAdd(&cur[b], 1);
        __builtin_nontemporal_store(pk, &pairs[p]);
    }
}

__global__ __launch_bounds__(256) void k_csr(const unsigned* __restrict__ pairs,
                                             const int* __restrict__ offg,
                                             int* __restrict__ csr,
                                             int* __restrict__ deg,
                                             float* __restrict__ dinv,
                                             int* __restrict__ offs) {
    __shared__ int cnt[NPB];
    __shared__ int loff[256];
    __shared__ int cur[NPB];
    const int b = blockIdx.x, t = threadIdx.x;
    const int s     = offg[b * NBLK];
    const int e_end = (b == NBUK - 1) ? NE : offg[(b + 1) * NBLK];
    const int nb0   = b * NPB;
    const int nnod  = min(NPB, NN - nb0);
    if (t < NPB) cnt[t] = 0;
    __syncthreads();
    for (int e = s + t; e < e_end; e += 256)
        atomicAdd(&cnt[pairs[e] >> 24], 1);
    __syncthreads();
    int v = (t < NPB) ? cnt[t] : 0;
    loff[t] = v;
    __syncthreads();
    for (int off = 1; off < 256; off <<= 1) {
        int u = (t >= off) ? loff[t - off] : 0;
        __syncthreads();
        loff[t] += u;
        __syncthreads();
    }
    int myoff = loff[t] - v;
    __syncthreads();
    loff[t] = myoff;
    if (t < NPB) cur[t] = 0;
    __syncthreads();
    if (t < nnod) {
        int node = nb0 + t;
        int dg = cnt[t];
        deg[node]  = dg;
        dinv[node] = rsqrtf((float)(dg + 1));
        offs[node] = s + myoff;
    }
    for (int e = s + t; e < e_end; e += 256) {
        unsigned pk = pairs[e];
        int li = pk >> 24;
        int p = atomicAdd(&cur[li], 1);
        csr[s + loff[li] + p] = (int)(pk & 0xffffffu);
    }
}

// ---------------- merged casts ----------------

#define XQ (NN * 32)   // x quads

__global__ void k_cast_all(const float* __restrict__ x, const float* __restrict__ dinv,
                           unsigned char* __restrict__ xs8,
                           const float* __restrict__ W1, unsigned short* __restrict__ Wt1,
                           const float* __restrict__ W2, unsigned short* __restrict__ Wt2) {
    int i = blockIdx.x * blockDim.x + threadIdx.x;
    if (i < XQ) {
        int nd = i >> 5;
        int q  = i & 31;
        float dv = dinv[nd];
        const float4 v = *(const float4*)&x[(size_t)nd * DIN + q * 4];
        uchar4 o;
        o.x = f32_to_fp8(v.x * dv); o.y = f32_to_fp8(v.y * dv);
        o.z = f32_to_fp8(v.z * dv); o.w = f32_to_fp8(v.w * dv);
        *(uchar4*)&xs8[(size_t)nd * DIN + q * 4] = o;
        return;
    }
    int j = i - XQ;
    if (j < DIN * HID) {
        int k = j >> 8, nc = j & 255;
        Wt1[nc * DIN + k] = f2bf(W1[j]);
    } else if (j < (DIN + HID) * HID) {
        int jj = j - DIN * HID;
        int k = jj >> 8, nc = jj & 255;
        Wt2[nc * HID + k] = f2bf(W2[jj]);
    }
}

// ---------------- MFMA GEMM: 128 rows x 256 cols per block, 8 waves, BK=64 ----------------
// fp8 A decoded to bf16 during staging (exact). A read/decoded ONCE per row-block.
// MODE 1: out_fp8[row*HID+col] = e4m3(dinv[row] * relu(acc + bias[col]))
// MODE 2: per-block psum[4][256] -> scratch (no global atomics)

template <int MODE>
__global__ __launch_bounds__(512) void k_gemm_mfma(const unsigned char* __restrict__ A8,
                                                   const unsigned short* __restrict__ Wt,
                                                   const float* __restrict__ dinv,
                                                   const float* __restrict__ bias,
                                                   void* __restrict__ outp,
                                                   const int* __restrict__ batch,
                                                   int M, int K) {
    __shared__ unsigned short As[128 * 72];   // stride 72 bf16 = 144B
    __shared__ unsigned short Bs[256 * 72];
    __shared__ float psum[4][256];
    __shared__ int gloc[128];
    const int t = threadIdx.x;
    const int lane = t & 63;
    const int wid = t >> 6;                   // 0..7
    const int wr = wid & 1, wc = wid >> 1;    // 2 row-tiles x 4 col-tiles of 64
    const int bm = blockIdx.x * 128;
    const int lr = lane & 15;
    const int ko = (lane >> 4) << 3;          // 0/8/16/24

    f32x4 acc[4][4] = {};

    const int arow = t >> 2;                  // 0..127
    const int akq  = (t & 3) << 4;            // 0/16/32/48 (fp8 ch)
    const int brow = t >> 1;                  // 0..255
    const int bkq  = (t & 1) << 5;            // 0/32 (bf16 ch)

    int g0 = 0, gend = 0;
    if (MODE == 2) {
        g0 = batch[bm];
        gend = batch[min(bm + 127, M - 1)];
        for (int i = t; i < 4 * 256; i += 512) ((float*)psum)[i] = 0.f;
        if (t < 128) gloc[t] = (bm + t < M) ? min(batch[bm + t] - g0, 3) : 0;
    }

    for (int kk = 0; kk < K; kk += 64) {
        {   // A tile: 128 rows x 64 fp8 -> decode to bf16
            int row = bm + arow;
            u32x4 v; v.x = v.y = v.z = v.w = 0u;
            if (row < M) v = *(const u32x4*)&A8[(size_t)row * K + kk + akq];
            *(int4*)&As[arow * 72 + akq]     = fp8x8_to_bf16x8(v.x, v.y);
            *(int4*)&As[arow * 72 + akq + 8] = fp8x8_to_bf16x8(v.z, v.w);
        }
        {   // B tile: 256 cols x 64 bf16
            const unsigned short* wsrc = &Wt[(size_t)brow * K + kk + bkq];
#pragma unroll
            for (int q = 0; q < 4; ++q)
                *(int4*)&Bs[brow * 72 + bkq + q * 8] = *(const int4*)&wsrc[q * 8];
        }
        __syncthreads();
#pragma unroll
        for (int ks = 0; ks < 64; ks += 32) {
            bf16x8 af[4], bfr[4];
#pragma unroll
            for (int mf = 0; mf < 4; ++mf)
                af[mf] = *(const bf16x8*)&As[(wr * 64 + mf * 16 + lr) * 72 + ks + ko];
#pragma unroll
            for (int nf = 0; nf < 4; ++nf)
                bfr[nf] = *(const bf16x8*)&Bs[(wc * 64 + nf * 16 + lr) * 72 + ks + ko];
#pragma unroll
            for (int mf = 0; mf < 4; ++mf)
#pragma unroll
                for (int nf = 0; nf < 4; ++nf)
                    acc[mf][nf] = __builtin_amdgcn_mfma_f32_16x16x32_bf16(af[mf], bfr[nf], acc[mf][nf], 0, 0, 0);
        }
        __syncthreads();
    }

    if (MODE == 1) {
        unsigned char* out8 = (unsigned char*)outp;
#pragma unroll
        for (int mf = 0; mf < 4; ++mf) {
#pragma unroll
            for (int b = 0; b < 4; ++b) {
                int row = bm + wr * 64 + mf * 16 + (lane >> 4) * 4 + b;
                if (row >= M) continue;
                float dv = dinv[row];
#pragma unroll
                for (int nf = 0; nf < 4; ++nf) {
                    int col = wc * 64 + nf * 16 + lr;
                    float v = fmaxf(acc[mf][nf][b] + bias[col], 0.f);
                    out8[(size_t)row * HID + col] = f32_to_fp8(dv * v);
                }
            }
        }
    } else {
        const int q4 = (lane >> 4) << 2;
        if (gend == g0) {
#pragma unroll
            for (int nf = 0; nf < 4; ++nf) {
                const int lcol = wc * 64 + nf * 16 + lr;
                const float bb = bias[lcol];
                float rsum = 0.f;
#pragma unroll
                for (int mf = 0; mf < 4; ++mf)
#pragma unroll
                    for (int b = 0; b < 4; ++b) {
                        int lrow = wr * 64 + mf * 16 + q4 + b;
                        if (bm + lrow < M) rsum += fmaxf(acc[mf][nf][b] + bb, 0.f);
                    }
                rsum += __shfl_xor(rsum, 16);
                rsum += __shfl_xor(rsum, 32);
                if ((lane >> 4) == 0) atomicAdd(&psum[0][lcol], rsum);
            }
        } else {
#pragma unroll
            for (int nf = 0; nf < 4; ++nf) {
                const int lcol = wc * 64 + nf * 16 + lr;
                const float bb = bias[lcol];
                float run = 0.f; int gcur = 0;
#pragma unroll
                for (int mf = 0; mf < 4; ++mf) {
#pragma unroll
                    for (int b = 0; b < 4; ++b) {
                        int lrow = wr * 64 + mf * 16 + q4 + b;
                        if (bm + lrow < M) {
                            int gl = gloc[lrow];
                            float v = fmaxf(acc[mf][nf][b] + bb, 0.f);
                            if (gl != gcur) {
                                if (run != 0.f) atomicAdd(&psum[gcur][lcol], run);
                                run = 0.f; gcur = gl;
                            }
                            run += v;
                        }
                    }
                }
                if (run != 0.f) atomicAdd(&psum[gcur][lcol], run);
            }
        }
        __syncthreads();
        float* scratch = (float*)outp;
        size_t base = (size_t)blockIdx.x * 1024;
        for (int i = t; i < 1024; i += 512)
            __builtin_nontemporal_store(((const float*)psum)[i], &scratch[base + i]);
    }
}

// ---------------- aggregation, 256 channels, fp8 gather, fp8 output ----------------

__global__ __launch_bounds__(256) void k_agg256(const unsigned char* __restrict__ hs,
                                                const int* __restrict__ csr,
                                                const int* __restrict__ offs,
                                                const int* __restrict__ deg,
                                                const float* __restrict__ dinv,
                                                unsigned char* __restrict__ out, int n) {
    int wid = threadIdx.x >> 6, lane = threadIdx.x & 63;
    int node = blockIdx.x * 4 + wid;
    if (node >= n) return;
    int c = lane << 2;
    float a0, a1, a2, a3;
    {
        unsigned u = *(const unsigned*)&hs[(size_t)node * HID + c];
        float f[4]; fp8x4_to_f32(u, f);
        a0 = f[0]; a1 = f[1]; a2 = f[2]; a3 = f[3];
    }
    int s0 = offs[node], cnt = deg[node];
    for (int base = 0; base < cnt; base += 64) {
        int nb = min(64, cnt - base);
        int idx = (lane < nb) ? __builtin_nontemporal_load(&csr[s0 + base + lane]) : 0;
        int i = 0;
        for (; i + 8 <= nb; i += 8) {
            unsigned v[8];
#pragma unroll
            for (int k = 0; k < 8; ++k) {
                int j = __shfl(idx, i + k);
                v[k] = *(const unsigned*)&hs[(size_t)j * HID + c];
            }
#pragma unroll
            for (int k = 0; k < 8; ++k) {
                float f[4]; fp8x4_to_f32(v[k], f);
                a0 += f[0]; a1 += f[1]; a2 += f[2]; a3 += f[3];
            }
        }
        for (; i + 4 <= nb; i += 4) {
            unsigned v[4];
#pragma unroll
            for (int k = 0; k < 4; ++k) {
                int j = __shfl(idx, i + k);
                v[k] = *(const unsigned*)&hs[(size_t)j * HID + c];
            }
#pragma unroll
            for (int k = 0; k < 4; ++k) {
                float f[4]; fp8x4_to_f32(v[k], f);
                a0 += f[0]; a1 += f[1]; a2 += f[2]; a3 += f[3];
            }
        }
        for (; i < nb; ++i) {
            int j = __shfl(idx, i);
            unsigned u = *(const unsigned*)&hs[(size_t)j * HID + c];
            float f[4]; fp8x4_to_f32(u, f);
            a0 += f[0]; a1 += f[1]; a2 += f[2]; a3 += f[3];
        }
    }
    float dv = dinv[node];
    uchar4 r;
    r.x = f32_to_fp8(dv * a0); r.y = f32_to_fp8(dv * a1);
    r.z = f32_to_fp8(dv * a2); r.w = f32_to_fp8(dv * a3);
    *(uchar4*)&out[(size_t)node * HID + c] = r;
}

// ---------------- aggregation, 128 channels, fp8 gather, fp8 output ----------------

__global__ __launch_bounds__(256) void k_agg128(const unsigned char* __restrict__ xs,
                                                const int* __restrict__ csr,
                                                const int* __restrict__ offs,
                                                const int* __restrict__ deg,
                                                const float* __restrict__ dinv,
                                                unsigned char* __restrict__ out, int n) {
    int wid = threadIdx.x >> 6, lane = threadIdx.x & 63;
    int node = blockIdx.x * 4 + wid;
    if (node >= n) return;
    int half = lane >> 5, l32 = lane & 31;
    int c = l32 << 2;
    float a0 = 0.f, a1 = 0.f, a2 = 0.f, a3 = 0.f;
    if (half == 0) {
        unsigned u = *(const unsigned*)&xs[(size_t)node * DIN + c];
        float f[4]; fp8x4_to_f32(u, f);
        a0 = f[0]; a1 = f[1]; a2 = f[2]; a3 = f[3];
    }
    int s0 = offs[node], cnt = deg[node];
    for (int base = 0; base < cnt; base += 64) {
        int nb = min(64, cnt - base);
        int idx = (lane < nb) ? __builtin_nontemporal_load(&csr[s0 + base + lane]) : 0;
        int i = 0;
        for (; i + 8 <= nb; i += 8) {
            unsigned v[4];
#pragma unroll
            for (int k = 0; k < 4; ++k) {
                int j = __shfl(idx, i + 2 * k + half);
                v[k] = *(const unsigned*)&xs[(size_t)j * DIN + c];
            }
#pragma unroll
            for (int k = 0; k < 4; ++k) {
                float f[4]; fp8x4_to_f32(v[k], f);
                a0 += f[0]; a1 += f[1]; a2 += f[2]; a3 += f[3];
            }
        }
        for (; i < nb; i += 2) {
            int e = i + half;
            int j = __shfl(idx, e < nb ? e : 0);
            if (e < nb) {
                unsigned u = *(const unsigned*)&xs[(size_t)j * DIN + c];
                float f[4]; fp8x4_to_f32(u, f);
                a0 += f[0]; a1 += f[1]; a2 += f[2]; a3 += f[3];
            }
        }
    }
    a0 += __shfl_xor(a0, 32);
    a1 += __shfl_xor(a1, 32);
    a2 += __shfl_xor(a2, 32);
    a3 += __shfl_xor(a3, 32);
    if (half == 0) {
        float dv = dinv[node];
        uchar4 r;
        r.x = f32_to_fp8(dv * a0); r.y = f32_to_fp8(dv * a1);
        r.z = f32_to_fp8(dv * a2); r.w = f32_to_fp8(dv * a3);
        *(uchar4*)&out[(size_t)node * DIN + c] = r;
    }
}

// ---------------- head MLP with fused pooled-reduction from scratch ----------------
// scratch layout: [NBR][4][256], row-block bx = node >> 7

__global__ __launch_bounds__(256) void k_mlp(const float* __restrict__ scratch,
                                             const int* __restrict__ batch,
                                             const float* __restrict__ countsf,
                                             const float* __restrict__ Wf1,
                                             const float* __restrict__ bf1,
                                             const float* __restrict__ Wf2,
                                             const float* __restrict__ bf2,
                                             float* __restrict__ out) {
    __shared__ float p[HID];
    __shared__ float z[HID];
    int g = blockIdx.x, t = threadIdx.x;
    int lo = 0, hi = NN;
    while (lo < hi) { int mid = (lo + hi) >> 1; if (batch[mid] < g) lo = mid + 1; else hi = mid; }
    int s = lo;
    lo = s; hi = NN;
    while (lo < hi) { int mid = (lo + hi) >> 1; if (batch[mid] <= g) lo = mid + 1; else hi = mid; }
    int e = lo;
    float sum = 0.f;
    if (e > s) {
        int bx0 = s >> 7, bx1 = (e - 1) >> 7;
        for (int bx = bx0; bx <= bx1; ++bx) {
            int gl = min(g - batch[bx << 7], 3);
            sum += scratch[(size_t)bx * 1024 + gl * 256 + t];
        }
    }
    float cnt = fmaxf(countsf[g], 1.0f);
    p[t] = sum / cnt;
    __syncthreads();
    float accz = bf1[t];
    for (int k = 0; k < HID; ++k)
        accz = fmaf(p[k], Wf1[k * HID + t], accz);
    z[t] = fmaxf(accz, 0.f);
    __syncthreads();
    if (t < NCLS) {
        float o = bf2[t];
        for (int k = 0; k < HID; ++k)
            o = fmaf(z[k], Wf2[k * NCLS + t], o);
        float sp = fmaxf(o, 0.f) + log1pf(expf(-fabsf(o)));
        out[g * NCLS + t] = sp + 0.001f;
    }
}

// ---------------- launch ----------------

extern "C" void kernel_launch(void* const* d_in, const int* in_sizes, int n_in,
                              void* d_out, int out_size, void* d_ws, size_t ws_size,
                              hipStream_t stream) {
    const float* x     = (const float*)d_in[0];
    const int*   ei    = (const int*)d_in[1];
    const int*   batch = (const int*)d_in[2];
    const float* W1    = (const float*)d_in[3];
    const float* b1    = (const float*)d_in[4];
    const float* W2    = (const float*)d_in[5];
    const float* b2    = (const float*)d_in[6];
    const float* Wf1   = (const float*)d_in[7];
    const float* bf1   = (const float*)d_in[8];
    const float* Wf2   = (const float*)d_in[9];
    const float* bf2   = (const float*)d_in[10];
    float* out = (float*)d_out;

    const int* srcv = ei;
    const int* dstv = ei + NE;

    char* p = (char*)d_ws;
    auto take = [&](size_t bytes) -> char* {
        char* q = p; p += (bytes + 255) & ~(size_t)255; return q;
    };
    // big0 (51.2MB): [xs8 fp8 12.8MB][xa8 fp8 12.8MB] early; r8 fp8 [NN][256] (25.6MB) later
    char* big0 = take((size_t)NN * HID * 2);
    // big1 (51.2MB): pairs u32 (6.4MB) early; h8 fp8 (25.6MB) + scratch (3.2MB) later
    char* big1 = take((size_t)NN * HID * 2);
    unsigned char*  xs8 = (unsigned char*)big0;                            // [NN][128] fp8
    unsigned char*  xa8 = (unsigned char*)(big0 + (size_t)NN * DIN);       // [NN][128] fp8
    unsigned char*  h8  = (unsigned char*)big1;                            // [NN][256] fp8
    unsigned char*  r8  = (unsigned char*)big0;                            // [NN][256] fp8 (xs8/xa8 dead)
    float* scratch = (float*)(big1 + (size_t)NN * HID);                    // [NBR][4][256] f32
    unsigned* pairs = (unsigned*)big1;                                     // dead before h8
    unsigned short* wt1  = (unsigned short*)take((size_t)DIN * HID * 2);
    unsigned short* wt2  = (unsigned short*)take((size_t)HID * HID * 2);
    int*   histg   = (int*)take((size_t)NHIST * 4);
    int*   bsum    = (int*)take(64 * 4);
    int*   boff    = (int*)take(64 * 4);
    int*   deg     = (int*)take((size_t)NN * 4);
    int*   offs    = (int*)take((size_t)NN * 4);
    int*   csr     = (int*)take((size_t)NE * 4);
    float* dinv    = (float*)take((size_t)NN * 4);
    float* countsf = (float*)take((size_t)NG * 4);

    k_hist<<<NBLK, 256, 0, stream>>>(dstv, histg);
    k_bsum2<<<64, 256, 0, stream>>>(histg, bsum);
    k_scanb2<<<1, 64, 0, stream>>>(bsum, boff, batch, countsf);
    k_offs2<<<64, 256, 0, stream>>>(histg, boff);
    k_scatter<<<NBLK, 256, 0, stream>>>(srcv, dstv, histg, pairs);
    k_csr<<<NBUK, 256, 0, stream>>>(pairs, histg, csr, deg, dinv, offs);

    int cast_total = XQ + (DIN + HID) * HID;
    k_cast_all<<<(cast_total + 255) / 256, 256, 0, stream>>>(x, dinv, xs8, W1, wt1, W2, wt2);

    // layer 1: fp8 gather -> xa8, GEMM1 (128x256 tile, writes h8 fp8)
    k_agg128<<<(NN + 3) / 4, 256, 0, stream>>>(xs8, csr, offs, deg, dinv, xa8, NN);
    k_gemm_mfma<1><<<NBR, 512, 0, stream>>>(xa8, wt1, dinv, b1, (void*)h8, batch, NN, DIN);
    // layer 2: fp8 gather -> r8, GEMM2 (psum -> scratch)
    k_agg256<<<(NN + 3) / 4, 256, 0, stream>>>(h8, csr, offs, deg, dinv, r8, NN);
    k_gemm_mfma<2><<<NBR, 512, 0, stream>>>(r8, wt2, dinv, b2, (void*)scratch, batch, NN, HID);

    // head: fused reduce + MLP
    k_mlp<<<NG, 256, 0, stream>>>(scratch, batch, countsf, Wf1, bf1, Wf2, bf2, out);
}

// Round 22
// 311.514 us; speedup vs baseline: 1.2481x; 1.0414x over previous
//
#include <hip/hip_runtime.h>
#include <math.h>

#define NN   100000
#define NE   1600000
#define DIN  128
#define HID  256
#define NG   64
#define NCLS 10

// counting-sort CSR build parameters
#define NBLK 128          // edge-chunk blocks (NE/NBLK = 12500 exactly)
#define EPB  (NE / NBLK)
#define NBUK 512          // dst buckets
#define NPB  196          // nodes per bucket (512*196 = 100352 >= NN)
#define NHIST (NBUK * NBLK)   // 65536 = 64 chunks x 1024
#define NBR  ((NN + 127) / 128)   // 782 row-blocks in the GEMM grid

#define XQ (NN * 32)                        // x quads
#define CAST_TOTAL (XQ + (DIN + HID) * HID) // cast work items
#define CAST_BLKS  ((CAST_TOTAL + 255) / 256)

using bf16x8 = __attribute__((ext_vector_type(8))) short;
using f32x4  = __attribute__((ext_vector_type(4))) float;
using f32x2  = __attribute__((ext_vector_type(2))) float;
using u32x2  = __attribute__((ext_vector_type(2))) unsigned int;
using u32x4  = __attribute__((ext_vector_type(4))) unsigned int;

static __device__ __forceinline__ unsigned short f2bf(float f) {
    unsigned u = __float_as_uint(f);
    u += 0x7fff + ((u >> 16) & 1);   // round-to-nearest-even
    return (unsigned short)(u >> 16);
}

// ---- OCP fp8 e4m3 helpers ----
static __device__ __forceinline__ unsigned char f32_to_fp8(float f) {
    float a = fminf(fabsf(f), 448.f);
    unsigned bits = __float_as_uint(a * 0x1p-120f);
    bits += 0x7ffff + ((bits >> 20) & 1);
    unsigned e4 = (bits >> 20) & 0x7f;
    return (unsigned char)(e4 | (f < 0.f ? 0x80u : 0u));
}
#if __has_builtin(__builtin_amdgcn_cvt_pk_f32_fp8)
#define HAVE_CVT_FP8 1
#endif
static __device__ __forceinline__ void fp8x4_to_f32(unsigned u, float* f) {
#ifdef HAVE_CVT_FP8
    f32x2 lo = __builtin_amdgcn_cvt_pk_f32_fp8((int)u, false);
    f32x2 hi = __builtin_amdgcn_cvt_pk_f32_fp8((int)u, true);
    f[0] = lo[0]; f[1] = lo[1]; f[2] = hi[0]; f[3] = hi[1];
#else
#pragma unroll
    for (int k = 0; k < 4; ++k) {
        unsigned b = (u >> (8 * k)) & 0xffu;
        unsigned bits = ((b & 0x80u) << 24) | ((b & 0x7fu) << 20);
        f[k] = __uint_as_float(bits) * 0x1p+120f;
    }
#endif
}
// 8 fp8 -> 8 bf16 packed (exact: e4m3 values are bf16-representable)
static __device__ __forceinline__ int4 fp8x8_to_bf16x8(unsigned lo, unsigned hi) {
    float f[8];
    fp8x4_to_f32(lo, f);
    fp8x4_to_f32(hi, f + 4);
    int4 r;
    r.x = (int)((__float_as_uint(f[0]) >> 16) | (__float_as_uint(f[1]) & 0xffff0000u));
    r.y = (int)((__float_as_uint(f[2]) >> 16) | (__float_as_uint(f[3]) & 0xffff0000u));
    r.z = (int)((__float_as_uint(f[4]) >> 16) | (__float_as_uint(f[5]) & 0xffff0000u));
    r.w = (int)((__float_as_uint(f[6]) >> 16) | (__float_as_uint(f[7]) & 0xffff0000u));
    return r;
}

// ---------------- k_hist + merged casts ----------------
// blocks [0, NBLK): per-(block,bucket) dst histogram
// blocks [NBLK, NBLK+CAST_BLKS): xs8 = fp8(x) (UNscaled; dinv deferred to agg128),
//                                wt1/wt2 = bf16 weight transposes

__global__ __launch_bounds__(256) void k_hist(const int* __restrict__ dst,
                                              int* __restrict__ histg,
                                              const float* __restrict__ x,
                                              unsigned char* __restrict__ xs8,
                                              const float* __restrict__ W1,
                                              unsigned short* __restrict__ Wt1,
                                              const float* __restrict__ W2,
                                              unsigned short* __restrict__ Wt2) {
    const int t = threadIdx.x;
    if (blockIdx.x >= NBLK) {
        int i = (blockIdx.x - NBLK) * 256 + t;
        if (i < XQ) {
            int nd = i >> 5;
            int q  = i & 31;
            const float4 v = *(const float4*)&x[(size_t)nd * DIN + q * 4];
            uchar4 o;
            o.x = f32_to_fp8(v.x); o.y = f32_to_fp8(v.y);
            o.z = f32_to_fp8(v.z); o.w = f32_to_fp8(v.w);
            *(uchar4*)&xs8[(size_t)nd * DIN + q * 4] = o;
        } else {
            int j = i - XQ;
            if (j < DIN * HID) {
                int k = j >> 8, nc = j & 255;
                Wt1[nc * DIN + k] = f2bf(W1[j]);
            } else if (j < (DIN + HID) * HID) {
                int jj = j - DIN * HID;
                int k = jj >> 8, nc = jj & 255;
                Wt2[nc * HID + k] = f2bf(W2[jj]);
            }
        }
        return;
    }
    __shared__ int h[NBUK];
    for (int i = t; i < NBUK; i += 256) h[i] = 0;
    __syncthreads();
    const int e0 = blockIdx.x * EPB, e1 = e0 + EPB;
    for (int e = e0 + t; e < e1; e += 256)
        atomicAdd(&h[(unsigned)__builtin_nontemporal_load(&dst[e]) / NPB], 1);
    __syncthreads();
    for (int i = t; i < NBUK; i += 256)
        histg[i * NBLK + blockIdx.x] = h[i];
}

__global__ __launch_bounds__(256) void k_bsum2(const int* __restrict__ d,
                                               int* __restrict__ bsum) {
    __shared__ int sd[256];
    int t = threadIdx.x;
    const int4 v = *(const int4*)&d[blockIdx.x * 1024 + t * 4];
    sd[t] = v.x + v.y + v.z + v.w;
    __syncthreads();
    for (int off = 128; off > 0; off >>= 1) {
        if (t < off) sd[t] += sd[t + off];
        __syncthreads();
    }
    if (t == 0) bsum[blockIdx.x] = sd[0];
}

__global__ void k_scanb2(const int* __restrict__ bsum, int* __restrict__ boff,
                         const int* __restrict__ batch, float* __restrict__ countsf) {
    __shared__ int tmp[64];
    int t = threadIdx.x;
    int v = bsum[t];
    tmp[t] = v; __syncthreads();
    for (int off = 1; off < 64; off <<= 1) {
        int u = (t >= off) ? tmp[t - off] : 0;
        __syncthreads();
        tmp[t] += u;
        __syncthreads();
    }
    boff[t] = tmp[t] - v;
    int g = t;
    int lo = 0, hi = NN;
    while (lo < hi) { int mid = (lo + hi) >> 1; if (batch[mid] < g) lo = mid + 1; else hi = mid; }
    int lb = lo;
    lo = 0; hi = NN;
    while (lo < hi) { int mid = (lo + hi) >> 1; if (batch[mid] <= g) lo = mid + 1; else hi = mid; }
    countsf[g] = (float)(lo - lb);
}

__global__ __launch_bounds__(256) void k_offs2(int* __restrict__ d,
                                               const int* __restrict__ boff) {
    __shared__ int ts[256];
    int t = threadIdx.x;
    int base = blockIdx.x * 1024 + t * 4;
    int4 v = *(const int4*)&d[base];
    int s = v.x + v.y + v.z + v.w;
    ts[t] = s; __syncthreads();
    for (int off = 1; off < 256; off <<= 1) {
        int u = (t >= off) ? ts[t - off] : 0;
        __syncthreads();
        ts[t] += u;
        __syncthreads();
    }
    int run = ts[t] - s + boff[blockIdx.x];
    int4 o;
    o.x = run; run += v.x;
    o.y = run; run += v.y;
    o.z = run; run += v.z;
    o.w = run; run += v.w;
    *(int4*)&d[base] = o;
}

__global__ __launch_bounds__(256) void k_scatter(const int* __restrict__ src,
                                                 const int* __restrict__ dst,
                                                 const int* __restrict__ offg,
                                                 unsigned* __restrict__ pairs) {
    __shared__ int cur[NBUK];
    const int t = threadIdx.x;
    for (int i = t; i < NBUK; i += 256) cur[i] = offg[i * NBLK + blockIdx.x];
    __syncthreads();
    const int e0 = blockIdx.x * EPB, e1 = e0 + EPB;
    for (int e = e0 + t; e < e1; e += 256) {
        int d = __builtin_nontemporal_load(&dst[e]);
        int sv = __builtin_nontemporal_load(&src[e]);
        int b = (unsigned)d / NPB;
        int li = d - b * NPB;
        unsigned pk = ((unsigned)li << 24) | (unsigned)sv;
        int p = atomicAdd(&cur[b], 1);
        __builtin_nontemporal_store(pk, &pairs[p]);
    }
}

__global__ __launch_bounds__(256) void k_csr(const unsigned* __restrict__ pairs,
                                             const int* __restrict__ offg,
                                             int* __restrict__ csr,
                                             int* __restrict__ deg,
                                             float* __restrict__ dinv,
                                             int* __restrict__ offs) {
    __shared__ int cnt[NPB];
    __shared__ int loff[256];
    __shared__ int cur[NPB];
    const int b = blockIdx.x, t = threadIdx.x;
    const int s     = offg[b * NBLK];
    const int e_end = (b == NBUK - 1) ? NE : offg[(b + 1) * NBLK];
    const int nb0   = b * NPB;
    const int nnod  = min(NPB, NN - nb0);
    if (t < NPB) cnt[t] = 0;
    __syncthreads();
    for (int e = s + t; e < e_end; e += 256)
        atomicAdd(&cnt[pairs[e] >> 24], 1);
    __syncthreads();
    int v = (t < NPB) ? cnt[t] : 0;
    loff[t] = v;
    __syncthreads();
    for (int off = 1; off < 256; off <<= 1) {
        int u = (t >= off) ? loff[t - off] : 0;
        __syncthreads();
        loff[t] += u;
        __syncthreads();
    }
    int myoff = loff[t] - v;
    __syncthreads();
    loff[t] = myoff;
    if (t < NPB) cur[t] = 0;
    __syncthreads();
    if (t < nnod) {
        int node = nb0 + t;
        int dg = cnt[t];
        deg[node]  = dg;
        dinv[node] = rsqrtf((float)(dg + 1));
        offs[node] = s + myoff;
    }
    for (int e = s + t; e < e_end; e += 256) {
        unsigned pk = pairs[e];
        int li = pk >> 24;
        int p = atomicAdd(&cur[li], 1);
        csr[s + loff[li] + p] = (int)(pk & 0xffffffu);
    }
}

// ---------------- MFMA GEMM: 128 rows x 256 cols per block, 8 waves, BK=64 ----------------
// MODE 1: out_fp8[row*HID+col] = e4m3(dinv[row] * relu(acc + bias[col]))
// MODE 2: per-block psum[4][256] -> scratch (no global atomics)

template <int MODE>
__global__ __launch_bounds__(512) void k_gemm_mfma(const unsigned char* __restrict__ A8,
                                                   const unsigned short* __restrict__ Wt,
                                                   const float* __restrict__ dinv,
                                                   const float* __restrict__ bias,
                                                   void* __restrict__ outp,
                                                   const int* __restrict__ batch,
                                                   int M, int K) {
    __shared__ unsigned short As[128 * 72];
    __shared__ unsigned short Bs[256 * 72];
    __shared__ float psum[4][256];
    __shared__ int gloc[128];
    const int t = threadIdx.x;
    const int lane = t & 63;
    const int wid = t >> 6;
    const int wr = wid & 1, wc = wid >> 1;
    const int bm = blockIdx.x * 128;
    const int lr = lane & 15;
    const int ko = (lane >> 4) << 3;

    f32x4 acc[4][4] = {};

    const int arow = t >> 2;
    const int akq  = (t & 3) << 4;
    const int brow = t >> 1;
    const int bkq  = (t & 1) << 5;

    int g0 = 0, gend = 0;
    if (MODE == 2) {
        g0 = batch[bm];
        gend = batch[min(bm + 127, M - 1)];
        for (int i = t; i < 4 * 256; i += 512) ((float*)psum)[i] = 0.f;
        if (t < 128) gloc[t] = (bm + t < M) ? min(batch[bm + t] - g0, 3) : 0;
    }

    for (int kk = 0; kk < K; kk += 64) {
        {
            int row = bm + arow;
            u32x4 v; v.x = v.y = v.z = v.w = 0u;
            if (row < M) v = *(const u32x4*)&A8[(size_t)row * K + kk + akq];
            *(int4*)&As[arow * 72 + akq]     = fp8x8_to_bf16x8(v.x, v.y);
            *(int4*)&As[arow * 72 + akq + 8] = fp8x8_to_bf16x8(v.z, v.w);
        }
        {
            const unsigned short* wsrc = &Wt[(size_t)brow * K + kk + bkq];
#pragma unroll
            for (int q = 0; q < 4; ++q)
                *(int4*)&Bs[brow * 72 + bkq + q * 8] = *(const int4*)&wsrc[q * 8];
        }
        __syncthreads();
#pragma unroll
        for (int ks = 0; ks < 64; ks += 32) {
            bf16x8 af[4], bfr[4];
#pragma unroll
            for (int mf = 0; mf < 4; ++mf)
                af[mf] = *(const bf16x8*)&As[(wr * 64 + mf * 16 + lr) * 72 + ks + ko];
#pragma unroll
            for (int nf = 0; nf < 4; ++nf)
                bfr[nf] = *(const bf16x8*)&Bs[(wc * 64 + nf * 16 + lr) * 72 + ks + ko];
#pragma unroll
            for (int mf = 0; mf < 4; ++mf)
#pragma unroll
                for (int nf = 0; nf < 4; ++nf)
                    acc[mf][nf] = __builtin_amdgcn_mfma_f32_16x16x32_bf16(af[mf], bfr[nf], acc[mf][nf], 0, 0, 0);
        }
        __syncthreads();
    }

    if (MODE == 1) {
        unsigned char* out8 = (unsigned char*)outp;
#pragma unroll
        for (int mf = 0; mf < 4; ++mf) {
#pragma unroll
            for (int b = 0; b < 4; ++b) {
                int row = bm + wr * 64 + mf * 16 + (lane >> 4) * 4 + b;
                if (row >= M) continue;
                float dv = dinv[row];
#pragma unroll
                for (int nf = 0; nf < 4; ++nf) {
                    int col = wc * 64 + nf * 16 + lr;
                    float v = fmaxf(acc[mf][nf][b] + bias[col], 0.f);
                    out8[(size_t)row * HID + col] = f32_to_fp8(dv * v);
                }
            }
        }
    } else {
        const int q4 = (lane >> 4) << 2;
        if (gend == g0) {
#pragma unroll
            for (int nf = 0; nf < 4; ++nf) {
                const int lcol = wc * 64 + nf * 16 + lr;
                const float bb = bias[lcol];
                float rsum = 0.f;
#pragma unroll
                for (int mf = 0; mf < 4; ++mf)
#pragma unroll
                    for (int b = 0; b < 4; ++b) {
                        int lrow = wr * 64 + mf * 16 + q4 + b;
                        if (bm + lrow < M) rsum += fmaxf(acc[mf][nf][b] + bb, 0.f);
                    }
                rsum += __shfl_xor(rsum, 16);
                rsum += __shfl_xor(rsum, 32);
                if ((lane >> 4) == 0) atomicAdd(&psum[0][lcol], rsum);
            }
        } else {
#pragma unroll
            for (int nf = 0; nf < 4; ++nf) {
                const int lcol = wc * 64 + nf * 16 + lr;
                const float bb = bias[lcol];
                float run = 0.f; int gcur = 0;
#pragma unroll
                for (int mf = 0; mf < 4; ++mf) {
#pragma unroll
                    for (int b = 0; b < 4; ++b) {
                        int lrow = wr * 64 + mf * 16 + q4 + b;
                        if (bm + lrow < M) {
                            int gl = gloc[lrow];
                            float v = fmaxf(acc[mf][nf][b] + bb, 0.f);
                            if (gl != gcur) {
                                if (run != 0.f) atomicAdd(&psum[gcur][lcol], run);
                                run = 0.f; gcur = gl;
                            }
                            run += v;
                        }
                    }
                }
                if (run != 0.f) atomicAdd(&psum[gcur][lcol], run);
            }
        }
        __syncthreads();
        float* scratch = (float*)outp;
        size_t base = (size_t)blockIdx.x * 1024;
        for (int i = t; i < 1024; i += 512)
            __builtin_nontemporal_store(((const float*)psum)[i], &scratch[base + i]);
    }
}

// ---------------- aggregation, 256 channels, fp8 gather, fp8 output ----------------

__global__ __launch_bounds__(256) void k_agg256(const unsigned char* __restrict__ hs,
                                                const int* __restrict__ csr,
                                                const int* __restrict__ offs,
                                                const int* __restrict__ deg,
                                                const float* __restrict__ dinv,
                                                unsigned char* __restrict__ out, int n) {
    int wid = threadIdx.x >> 6, lane = threadIdx.x & 63;
    int node = blockIdx.x * 4 + wid;
    if (node >= n) return;
    int c = lane << 2;
    float a0, a1, a2, a3;
    {
        unsigned u = *(const unsigned*)&hs[(size_t)node * HID + c];
        float f[4]; fp8x4_to_f32(u, f);
        a0 = f[0]; a1 = f[1]; a2 = f[2]; a3 = f[3];
    }
    int s0 = offs[node], cnt = deg[node];
    for (int base = 0; base < cnt; base += 64) {
        int nb = min(64, cnt - base);
        int idx = (lane < nb) ? __builtin_nontemporal_load(&csr[s0 + base + lane]) : 0;
        int i = 0;
        for (; i + 8 <= nb; i += 8) {
            unsigned v[8];
#pragma unroll
            for (int k = 0; k < 8; ++k) {
                int j = __shfl(idx, i + k);
                v[k] = *(const unsigned*)&hs[(size_t)j * HID + c];
            }
#pragma unroll
            for (int k = 0; k < 8; ++k) {
                float f[4]; fp8x4_to_f32(v[k], f);
                a0 += f[0]; a1 += f[1]; a2 += f[2]; a3 += f[3];
            }
        }
        for (; i + 4 <= nb; i += 4) {
            unsigned v[4];
#pragma unroll
            for (int k = 0; k < 4; ++k) {
                int j = __shfl(idx, i + k);
                v[k] = *(const unsigned*)&hs[(size_t)j * HID + c];
            }
#pragma unroll
            for (int k = 0; k < 4; ++k) {
                float f[4]; fp8x4_to_f32(v[k], f);
                a0 += f[0]; a1 += f[1]; a2 += f[2]; a3 += f[3];
            }
        }
        for (; i < nb; ++i) {
            int j = __shfl(idx, i);
            unsigned u = *(const unsigned*)&hs[(size_t)j * HID + c];
            float f[4]; fp8x4_to_f32(u, f);
            a0 += f[0]; a1 += f[1]; a2 += f[2]; a3 += f[3];
        }
    }
    float dv = dinv[node];
    uchar4 r;
    r.x = f32_to_fp8(dv * a0); r.y = f32_to_fp8(dv * a1);
    r.z = f32_to_fp8(dv * a2); r.w = f32_to_fp8(dv * a3);
    *(uchar4*)&out[(size_t)node * HID + c] = r;
}

// ---------------- aggregation, 128 channels, fp8 gather (UNscaled xs8), fp8 output --------
// a = dinv[node]*x[node] + sum_s dinv[s]*x[s]; out = fp8(dinv[node] * a)

__global__ __launch_bounds__(256) void k_agg128(const unsigned char* __restrict__ xs,
                                                const int* __restrict__ csr,
                                                const int* __restrict__ offs,
                                                const int* __restrict__ deg,
                                                const float* __restrict__ dinv,
                                                unsigned char* __restrict__ out, int n) {
    int wid = threadIdx.x >> 6, lane = threadIdx.x & 63;
    int node = blockIdx.x * 4 + wid;
    if (node >= n) return;
    int half = lane >> 5, l32 = lane & 31;
    int c = l32 << 2;
    float dvn = dinv[node];
    float a0 = 0.f, a1 = 0.f, a2 = 0.f, a3 = 0.f;
    if (half == 0) {
        unsigned u = *(const unsigned*)&xs[(size_t)node * DIN + c];
        float f[4]; fp8x4_to_f32(u, f);
        a0 = dvn * f[0]; a1 = dvn * f[1]; a2 = dvn * f[2]; a3 = dvn * f[3];
    }
    int s0 = offs[node], cnt = deg[node];
    for (int base = 0; base < cnt; base += 64) {
        int nb = min(64, cnt - base);
        int idx = (lane < nb) ? __builtin_nontemporal_load(&csr[s0 + base + lane]) : 0;
        int i = 0;
        for (; i + 8 <= nb; i += 8) {
            unsigned v[4]; float dvj[4];
#pragma unroll
            for (int k = 0; k < 4; ++k) {
                int j = __shfl(idx, i + 2 * k + half);
                v[k] = *(const unsigned*)&xs[(size_t)j * DIN + c];
                dvj[k] = dinv[j];
            }
#pragma unroll
            for (int k = 0; k < 4; ++k) {
                float f[4]; fp8x4_to_f32(v[k], f);
                a0 = fmaf(dvj[k], f[0], a0); a1 = fmaf(dvj[k], f[1], a1);
                a2 = fmaf(dvj[k], f[2], a2); a3 = fmaf(dvj[k], f[3], a3);
            }
        }
        for (; i < nb; i += 2) {
            int e = i + half;
            int j = __shfl(idx, e < nb ? e : 0);
            if (e < nb) {
                unsigned u = *(const unsigned*)&xs[(size_t)j * DIN + c];
                float dvj = dinv[j];
                float f[4]; fp8x4_to_f32(u, f);
                a0 = fmaf(dvj, f[0], a0); a1 = fmaf(dvj, f[1], a1);
                a2 = fmaf(dvj, f[2], a2); a3 = fmaf(dvj, f[3], a3);
            }
        }
    }
    a0 += __shfl_xor(a0, 32);
    a1 += __shfl_xor(a1, 32);
    a2 += __shfl_xor(a2, 32);
    a3 += __shfl_xor(a3, 32);
    if (half == 0) {
        uchar4 r;
        r.x = f32_to_fp8(dvn * a0); r.y = f32_to_fp8(dvn * a1);
        r.z = f32_to_fp8(dvn * a2); r.w = f32_to_fp8(dvn * a3);
        *(uchar4*)&out[(size_t)node * DIN + c] = r;
    }
}

// ---------------- head MLP with fused pooled-reduction from scratch ----------------

__global__ __launch_bounds__(256) void k_mlp(const float* __restrict__ scratch,
                                             const int* __restrict__ batch,
                                             const float* __restrict__ countsf,
                                             const float* __restrict__ Wf1,
                                             const float* __restrict__ bf1,
                                             const float* __restrict__ Wf2,
                                             const float* __restrict__ bf2,
                                             float* __restrict__ out) {
    __shared__ float p[HID];
    __shared__ float z[HID];
    int g = blockIdx.x, t = threadIdx.x;
    int lo = 0, hi = NN;
    while (lo < hi) { int mid = (lo + hi) >> 1; if (batch[mid] < g) lo = mid + 1; else hi = mid; }
    int s = lo;
    lo = s; hi = NN;
    while (lo < hi) { int mid = (lo + hi) >> 1; if (batch[mid] <= g) lo = mid + 1; else hi = mid; }
    int e = lo;
    float sum = 0.f;
    if (e > s) {
        int bx0 = s >> 7, bx1 = (e - 1) >> 7;
        for (int bx = bx0; bx <= bx1; ++bx) {
            int gl = min(g - batch[bx << 7], 3);
            sum += scratch[(size_t)bx * 1024 + gl * 256 + t];
        }
    }
    float cnt = fmaxf(countsf[g], 1.0f);
    p[t] = sum / cnt;
    __syncthreads();
    float accz = bf1[t];
    for (int k = 0; k < HID; ++k)
        accz = fmaf(p[k], Wf1[k * HID + t], accz);
    z[t] = fmaxf(accz, 0.f);
    __syncthreads();
    if (t < NCLS) {
        float o = bf2[t];
        for (int k = 0; k < HID; ++k)
            o = fmaf(z[k], Wf2[k * NCLS + t], o);
        float sp = fmaxf(o, 0.f) + log1pf(expf(-fabsf(o)));
        out[g * NCLS + t] = sp + 0.001f;
    }
}

// ---------------- launch ----------------

extern "C" void kernel_launch(void* const* d_in, const int* in_sizes, int n_in,
                              void* d_out, int out_size, void* d_ws, size_t ws_size,
                              hipStream_t stream) {
    const float* x     = (const float*)d_in[0];
    const int*   ei    = (const int*)d_in[1];
    const int*   batch = (const int*)d_in[2];
    const float* W1    = (const float*)d_in[3];
    const float* b1    = (const float*)d_in[4];
    const float* W2    = (const float*)d_in[5];
    const float* b2    = (const float*)d_in[6];
    const float* Wf1   = (const float*)d_in[7];
    const float* bf1   = (const float*)d_in[8];
    const float* Wf2   = (const float*)d_in[9];
    const float* bf2   = (const float*)d_in[10];
    float* out = (float*)d_out;

    const int* srcv = ei;
    const int* dstv = ei + NE;

    char* p = (char*)d_ws;
    auto take = [&](size_t bytes) -> char* {
        char* q = p; p += (bytes + 255) & ~(size_t)255; return q;
    };
    // big0 (51.2MB): [xs8 fp8 12.8MB][xa8 fp8 12.8MB] early; r8 fp8 [NN][256] later
    char* big0 = take((size_t)NN * HID * 2);
    // big1 (51.2MB): pairs u32 (6.4MB) early; h8 fp8 (25.6MB) + scratch (3.2MB) later
    char* big1 = take((size_t)NN * HID * 2);
    unsigned char*  xs8 = (unsigned char*)big0;                            // [NN][128] fp8 (UNscaled)
    unsigned char*  xa8 = (unsigned char*)(big0 + (size_t)NN * DIN);       // [NN][128] fp8
    unsigned char*  h8  = (unsigned char*)big1;                            // [NN][256] fp8
    unsigned char*  r8  = (unsigned char*)big0;                            // [NN][256] fp8 (xs8/xa8 dead)
    float* scratch = (float*)(big1 + (size_t)NN * HID);                    // [NBR][4][256] f32
    unsigned* pairs = (unsigned*)big1;                                     // dead before h8
    unsigned short* wt1  = (unsigned short*)take((size_t)DIN * HID * 2);
    unsigned short* wt2  = (unsigned short*)take((size_t)HID * HID * 2);
    int*   histg   = (int*)take((size_t)NHIST * 4);
    int*   bsum    = (int*)take(64 * 4);
    int*   boff    = (int*)take(64 * 4);
    int*   deg     = (int*)take((size_t)NN * 4);
    int*   offs    = (int*)take((size_t)NN * 4);
    int*   csr     = (int*)take((size_t)NE * 4);
    float* dinv    = (float*)take((size_t)NN * 4);
    float* countsf = (float*)take((size_t)NG * 4);

    // hist + all casts in one launch (cast blocks run concurrently with hist blocks)
    k_hist<<<NBLK + CAST_BLKS, 256, 0, stream>>>(dstv, histg, x, xs8, W1, wt1, W2, wt2);
    k_bsum2<<<64, 256, 0, stream>>>(histg, bsum);
    k_scanb2<<<1, 64, 0, stream>>>(bsum, boff, batch, countsf);
    k_offs2<<<64, 256, 0, stream>>>(histg, boff);
    k_scatter<<<NBLK, 256, 0, stream>>>(srcv, dstv, histg, pairs);
    k_csr<<<NBUK, 256, 0, stream>>>(pairs, histg, csr, deg, dinv, offs);

    // layer 1: fp8 gather (dinv deferred) -> xa8, GEMM1 (writes h8 fp8)
    k_agg128<<<(NN + 3) / 4, 256, 0, stream>>>(xs8, csr, offs, deg, dinv, xa8, NN);
    k_gemm_mfma<1><<<NBR, 512, 0, stream>>>(xa8, wt1, dinv, b1, (void*)h8, batch, NN, DIN);
    // layer 2: fp8 gather -> r8, GEMM2 (psum -> scratch)
    k_agg256<<<(NN + 3) / 4, 256, 0, stream>>>(h8, csr, offs, deg, dinv, r8, NN);
    k_gemm_mfma<2><<<NBR, 512, 0, stream>>>(r8, wt2, dinv, b2, (void*)scratch, batch, NN, HID);

    // head: fused reduce + MLP
    k_mlp<<<NG, 256, 0, stream>>>(scratch, batch, countsf, Wf1, bf1, Wf2, bf2, out);
}

// Round 23
// 310.326 us; speedup vs baseline: 1.2529x; 1.0038x over previous
//
#include <hip/hip_runtime.h>
#include <math.h>

#define NN   100000
#define NE   1600000
#define DIN  128
#define HID  256
#define NG   64
#define NCLS 10

// counting-sort CSR build parameters
#define NBLK 128          // edge-chunk blocks (NE/NBLK = 12500 exactly)
#define EPB  (NE / NBLK)
#define NBUK 512          // dst buckets
#define NPB  196          // nodes per bucket (512*196 = 100352 >= NN)
#define NHIST (NBUK * NBLK)   // 65536 = 64 chunks x 1024
#define NBR  ((NN + 127) / 128)   // 782 row-blocks in the GEMM grid

#define XQ (NN * 32)                        // x quads
#define CAST_TOTAL (XQ + (DIN + HID) * HID) // cast work items
#define CAST_BLKS  ((CAST_TOTAL + 255) / 256)

using bf16x8 = __attribute__((ext_vector_type(8))) short;
using f32x4  = __attribute__((ext_vector_type(4))) float;
using f32x2  = __attribute__((ext_vector_type(2))) float;
using u32x2  = __attribute__((ext_vector_type(2))) unsigned int;
using u32x4  = __attribute__((ext_vector_type(4))) unsigned int;

static __device__ __forceinline__ unsigned short f2bf(float f) {
    unsigned u = __float_as_uint(f);
    u += 0x7fff + ((u >> 16) & 1);   // round-to-nearest-even
    return (unsigned short)(u >> 16);
}

// ---- OCP fp8 e4m3 helpers ----
static __device__ __forceinline__ unsigned char f32_to_fp8(float f) {
    float a = fminf(fabsf(f), 448.f);
    unsigned bits = __float_as_uint(a * 0x1p-120f);
    bits += 0x7ffff + ((bits >> 20) & 1);
    unsigned e4 = (bits >> 20) & 0x7f;
    return (unsigned char)(e4 | (f < 0.f ? 0x80u : 0u));
}
#if __has_builtin(__builtin_amdgcn_cvt_pk_f32_fp8)
#define HAVE_CVT_FP8 1
#endif
static __device__ __forceinline__ void fp8x4_to_f32(unsigned u, float* f) {
#ifdef HAVE_CVT_FP8
    f32x2 lo = __builtin_amdgcn_cvt_pk_f32_fp8((int)u, false);
    f32x2 hi = __builtin_amdgcn_cvt_pk_f32_fp8((int)u, true);
    f[0] = lo[0]; f[1] = lo[1]; f[2] = hi[0]; f[3] = hi[1];
#else
#pragma unroll
    for (int k = 0; k < 4; ++k) {
        unsigned b = (u >> (8 * k)) & 0xffu;
        unsigned bits = ((b & 0x80u) << 24) | ((b & 0x7fu) << 20);
        f[k] = __uint_as_float(bits) * 0x1p+120f;
    }
#endif
}
// 8 fp8 -> 8 bf16 packed (exact: e4m3 values are bf16-representable)
static __device__ __forceinline__ int4 fp8x8_to_bf16x8(unsigned lo, unsigned hi) {
    float f[8];
    fp8x4_to_f32(lo, f);
    fp8x4_to_f32(hi, f + 4);
    int4 r;
    r.x = (int)((__float_as_uint(f[0]) >> 16) | (__float_as_uint(f[1]) & 0xffff0000u));
    r.y = (int)((__float_as_uint(f[2]) >> 16) | (__float_as_uint(f[3]) & 0xffff0000u));
    r.z = (int)((__float_as_uint(f[4]) >> 16) | (__float_as_uint(f[5]) & 0xffff0000u));
    r.w = (int)((__float_as_uint(f[6]) >> 16) | (__float_as_uint(f[7]) & 0xffff0000u));
    return r;
}

// ---------------- k_hist + merged casts ----------------
// blocks [0, NBLK): per-(block,bucket) dst histogram
// blocks [NBLK, NBLK+CAST_BLKS): xs8 = fp8(x) (UNscaled; dinv deferred to agg128),
//                                wt1/wt2 = bf16 weight transposes

__global__ __launch_bounds__(256) void k_hist(const int* __restrict__ dst,
                                              int* __restrict__ histg,
                                              const float* __restrict__ x,
                                              unsigned char* __restrict__ xs8,
                                              const float* __restrict__ W1,
                                              unsigned short* __restrict__ Wt1,
                                              const float* __restrict__ W2,
                                              unsigned short* __restrict__ Wt2) {
    const int t = threadIdx.x;
    if (blockIdx.x >= NBLK) {
        int i = (blockIdx.x - NBLK) * 256 + t;
        if (i < XQ) {
            int nd = i >> 5;
            int q  = i & 31;
            const float4 v = *(const float4*)&x[(size_t)nd * DIN + q * 4];
            uchar4 o;
            o.x = f32_to_fp8(v.x); o.y = f32_to_fp8(v.y);
            o.z = f32_to_fp8(v.z); o.w = f32_to_fp8(v.w);
            *(uchar4*)&xs8[(size_t)nd * DIN + q * 4] = o;
        } else {
            int j = i - XQ;
            if (j < DIN * HID) {
                int k = j >> 8, nc = j & 255;
                Wt1[nc * DIN + k] = f2bf(W1[j]);
            } else if (j < (DIN + HID) * HID) {
                int jj = j - DIN * HID;
                int k = jj >> 8, nc = jj & 255;
                Wt2[nc * HID + k] = f2bf(W2[jj]);
            }
        }
        return;
    }
    __shared__ int h[NBUK];
    for (int i = t; i < NBUK; i += 256) h[i] = 0;
    __syncthreads();
    const int e0 = blockIdx.x * EPB, e1 = e0 + EPB;
    for (int e = e0 + t; e < e1; e += 256)
        atomicAdd(&h[(unsigned)__builtin_nontemporal_load(&dst[e]) / NPB], 1);
    __syncthreads();
    for (int i = t; i < NBUK; i += 256)
        histg[i * NBLK + blockIdx.x] = h[i];
}

__global__ __launch_bounds__(256) void k_bsum2(const int* __restrict__ d,
                                               int* __restrict__ bsum) {
    __shared__ int sd[256];
    int t = threadIdx.x;
    const int4 v = *(const int4*)&d[blockIdx.x * 1024 + t * 4];
    sd[t] = v.x + v.y + v.z + v.w;
    __syncthreads();
    for (int off = 128; off > 0; off >>= 1) {
        if (t < off) sd[t] += sd[t + off];
        __syncthreads();
    }
    if (t == 0) bsum[blockIdx.x] = sd[0];
}

__global__ void k_scanb2(const int* __restrict__ bsum, int* __restrict__ boff,
                         const int* __restrict__ batch, float* __restrict__ countsf) {
    __shared__ int tmp[64];
    int t = threadIdx.x;
    int v = bsum[t];
    tmp[t] = v; __syncthreads();
    for (int off = 1; off < 64; off <<= 1) {
        int u = (t >= off) ? tmp[t - off] : 0;
        __syncthreads();
        tmp[t] += u;
        __syncthreads();
    }
    boff[t] = tmp[t] - v;
    int g = t;
    int lo = 0, hi = NN;
    while (lo < hi) { int mid = (lo + hi) >> 1; if (batch[mid] < g) lo = mid + 1; else hi = mid; }
    int lb = lo;
    lo = 0; hi = NN;
    while (lo < hi) { int mid = (lo + hi) >> 1; if (batch[mid] <= g) lo = mid + 1; else hi = mid; }
    countsf[g] = (float)(lo - lb);
}

__global__ __launch_bounds__(256) void k_offs2(int* __restrict__ d,
                                               const int* __restrict__ boff) {
    __shared__ int ts[256];
    int t = threadIdx.x;
    int base = blockIdx.x * 1024 + t * 4;
    int4 v = *(const int4*)&d[base];
    int s = v.x + v.y + v.z + v.w;
    ts[t] = s; __syncthreads();
    for (int off = 1; off < 256; off <<= 1) {
        int u = (t >= off) ? ts[t - off] : 0;
        __syncthreads();
        ts[t] += u;
        __syncthreads();
    }
    int run = ts[t] - s + boff[blockIdx.x];
    int4 o;
    o.x = run; run += v.x;
    o.y = run; run += v.y;
    o.z = run; run += v.z;
    o.w = run; run += v.w;
    *(int4*)&d[base] = o;
}

__global__ __launch_bounds__(256) void k_scatter(const int* __restrict__ src,
                                                 const int* __restrict__ dst,
                                                 const int* __restrict__ offg,
                                                 unsigned* __restrict__ pairs) {
    __shared__ int cur[NBUK];
    const int t = threadIdx.x;
    for (int i = t; i < NBUK; i += 256) cur[i] = offg[i * NBLK + blockIdx.x];
    __syncthreads();
    const int e0 = blockIdx.x * EPB, e1 = e0 + EPB;
    for (int e = e0 + t; e < e1; e += 256) {
        int d = __builtin_nontemporal_load(&dst[e]);
        int sv = __builtin_nontemporal_load(&src[e]);
        int b = (unsigned)d / NPB;
        int li = d - b * NPB;
        unsigned pk = ((unsigned)li << 24) | (unsigned)sv;
        int p = atomicAdd(&cur[b], 1);
        __builtin_nontemporal_store(pk, &pairs[p]);
    }
}

__global__ __launch_bounds__(256) void k_csr(const unsigned* __restrict__ pairs,
                                             const int* __restrict__ offg,
                                             int* __restrict__ csr,
                                             int* __restrict__ deg,
                                             float* __restrict__ dinv,
                                             int* __restrict__ offs) {
    __shared__ int cnt[NPB];
    __shared__ int loff[256];
    __shared__ int cur[NPB];
    const int b = blockIdx.x, t = threadIdx.x;
    const int s     = offg[b * NBLK];
    const int e_end = (b == NBUK - 1) ? NE : offg[(b + 1) * NBLK];
    const int nb0   = b * NPB;
    const int nnod  = min(NPB, NN - nb0);
    if (t < NPB) cnt[t] = 0;
    __syncthreads();
    for (int e = s + t; e < e_end; e += 256)
        atomicAdd(&cnt[pairs[e] >> 24], 1);
    __syncthreads();
    int v = (t < NPB) ? cnt[t] : 0;
    loff[t] = v;
    __syncthreads();
    for (int off = 1; off < 256; off <<= 1) {
        int u = (t >= off) ? loff[t - off] : 0;
        __syncthreads();
        loff[t] += u;
        __syncthreads();
    }
    int myoff = loff[t] - v;
    __syncthreads();
    loff[t] = myoff;
    if (t < NPB) cur[t] = 0;
    __syncthreads();
    if (t < nnod) {
        int node = nb0 + t;
        int dg = cnt[t];
        deg[node]  = dg;
        dinv[node] = rsqrtf((float)(dg + 1));
        offs[node] = s + myoff;
    }
    for (int e = s + t; e < e_end; e += 256) {
        unsigned pk = pairs[e];
        int li = pk >> 24;
        int p = atomicAdd(&cur[li], 1);
        csr[s + loff[li] + p] = (int)(pk & 0xffffffu);
    }
}

// ---------------- MFMA GEMM: 128 rows x 256 cols per block, 8 waves, BK=64 ----------------
// MODE 1: out_fp8[row*HID+col] = e4m3(dinv[row] * relu(acc + bias[col]))
// MODE 2: per-block psum[4][256] -> scratch (no global atomics)

template <int MODE>
__global__ __launch_bounds__(512) void k_gemm_mfma(const unsigned char* __restrict__ A8,
                                                   const unsigned short* __restrict__ Wt,
                                                   const float* __restrict__ dinv,
                                                   const float* __restrict__ bias,
                                                   void* __restrict__ outp,
                                                   const int* __restrict__ batch,
                                                   int M, int K) {
    __shared__ unsigned short As[128 * 72];
    __shared__ unsigned short Bs[256 * 72];
    __shared__ float psum[4][256];
    __shared__ int gloc[128];
    const int t = threadIdx.x;
    const int lane = t & 63;
    const int wid = t >> 6;
    const int wr = wid & 1, wc = wid >> 1;
    const int bm = blockIdx.x * 128;
    const int lr = lane & 15;
    const int ko = (lane >> 4) << 3;

    f32x4 acc[4][4] = {};

    const int arow = t >> 2;
    const int akq  = (t & 3) << 4;
    const int brow = t >> 1;
    const int bkq  = (t & 1) << 5;

    int g0 = 0, gend = 0;
    if (MODE == 2) {
        g0 = batch[bm];
        gend = batch[min(bm + 127, M - 1)];
        for (int i = t; i < 4 * 256; i += 512) ((float*)psum)[i] = 0.f;
        if (t < 128) gloc[t] = (bm + t < M) ? min(batch[bm + t] - g0, 3) : 0;
    }

    for (int kk = 0; kk < K; kk += 64) {
        {
            int row = bm + arow;
            u32x4 v; v.x = v.y = v.z = v.w = 0u;
            if (row < M) v = *(const u32x4*)&A8[(size_t)row * K + kk + akq];
            *(int4*)&As[arow * 72 + akq]     = fp8x8_to_bf16x8(v.x, v.y);
            *(int4*)&As[arow * 72 + akq + 8] = fp8x8_to_bf16x8(v.z, v.w);
        }
        {
            const unsigned short* wsrc = &Wt[(size_t)brow * K + kk + bkq];
#pragma unroll
            for (int q = 0; q < 4; ++q)
                *(int4*)&Bs[brow * 72 + bkq + q * 8] = *(const int4*)&wsrc[q * 8];
        }
        __syncthreads();
#pragma unroll
        for (int ks = 0; ks < 64; ks += 32) {
            bf16x8 af[4], bfr[4];
#pragma unroll
            for (int mf = 0; mf < 4; ++mf)
                af[mf] = *(const bf16x8*)&As[(wr * 64 + mf * 16 + lr) * 72 + ks + ko];
#pragma unroll
            for (int nf = 0; nf < 4; ++nf)
                bfr[nf] = *(const bf16x8*)&Bs[(wc * 64 + nf * 16 + lr) * 72 + ks + ko];
#pragma unroll
            for (int mf = 0; mf < 4; ++mf)
#pragma unroll
                for (int nf = 0; nf < 4; ++nf)
                    acc[mf][nf] = __builtin_amdgcn_mfma_f32_16x16x32_bf16(af[mf], bfr[nf], acc[mf][nf], 0, 0, 0);
        }
        __syncthreads();
    }

    if (MODE == 1) {
        unsigned char* out8 = (unsigned char*)outp;
#pragma unroll
        for (int mf = 0; mf < 4; ++mf) {
#pragma unroll
            for (int b = 0; b < 4; ++b) {
                int row = bm + wr * 64 + mf * 16 + (lane >> 4) * 4 + b;
                if (row >= M) continue;
                float dv = dinv[row];
#pragma unroll
                for (int nf = 0; nf < 4; ++nf) {
                    int col = wc * 64 + nf * 16 + lr;
                    float v = fmaxf(acc[mf][nf][b] + bias[col], 0.f);
                    out8[(size_t)row * HID + col] = f32_to_fp8(dv * v);
                }
            }
        }
    } else {
        const int q4 = (lane >> 4) << 2;
        if (gend == g0) {
#pragma unroll
            for (int nf = 0; nf < 4; ++nf) {
                const int lcol = wc * 64 + nf * 16 + lr;
                const float bb = bias[lcol];
                float rsum = 0.f;
#pragma unroll
                for (int mf = 0; mf < 4; ++mf)
#pragma unroll
                    for (int b = 0; b < 4; ++b) {
                        int lrow = wr * 64 + mf * 16 + q4 + b;
                        if (bm + lrow < M) rsum += fmaxf(acc[mf][nf][b] + bb, 0.f);
                    }
                rsum += __shfl_xor(rsum, 16);
                rsum += __shfl_xor(rsum, 32);
                if ((lane >> 4) == 0) atomicAdd(&psum[0][lcol], rsum);
            }
        } else {
#pragma unroll
            for (int nf = 0; nf < 4; ++nf) {
                const int lcol = wc * 64 + nf * 16 + lr;
                const float bb = bias[lcol];
                float run = 0.f; int gcur = 0;
#pragma unroll
                for (int mf = 0; mf < 4; ++mf) {
#pragma unroll
                    for (int b = 0; b < 4; ++b) {
                        int lrow = wr * 64 + mf * 16 + q4 + b;
                        if (bm + lrow < M) {
                            int gl = gloc[lrow];
                            float v = fmaxf(acc[mf][nf][b] + bb, 0.f);
                            if (gl != gcur) {
                                if (run != 0.f) atomicAdd(&psum[gcur][lcol], run);
                                run = 0.f; gcur = gl;
                            }
                            run += v;
                        }
                    }
                }
                if (run != 0.f) atomicAdd(&psum[gcur][lcol], run);
            }
        }
        __syncthreads();
        float* scratch = (float*)outp;
        size_t base = (size_t)blockIdx.x * 1024;
        for (int i = t; i < 1024; i += 512)
            __builtin_nontemporal_store(((const float*)psum)[i], &scratch[base + i]);
    }
}

// ---------------- aggregation, 256 channels, fp8 gather, fp8 output ----------------

__global__ __launch_bounds__(256) void k_agg256(const unsigned char* __restrict__ hs,
                                                const int* __restrict__ csr,
                                                const int* __restrict__ offs,
                                                const int* __restrict__ deg,
                                                const float* __restrict__ dinv,
                                                unsigned char* __restrict__ out, int n) {
    int wid = threadIdx.x >> 6, lane = threadIdx.x & 63;
    int node = blockIdx.x * 4 + wid;
    if (node >= n) return;
    int c = lane << 2;
    float a0, a1, a2, a3;
    {
        unsigned u = *(const unsigned*)&hs[(size_t)node * HID + c];
        float f[4]; fp8x4_to_f32(u, f);
        a0 = f[0]; a1 = f[1]; a2 = f[2]; a3 = f[3];
    }
    int s0 = offs[node], cnt = deg[node];
    for (int base = 0; base < cnt; base += 64) {
        int nb = min(64, cnt - base);
        int idx = (lane < nb) ? __builtin_nontemporal_load(&csr[s0 + base + lane]) : 0;
        int i = 0;
        for (; i + 8 <= nb; i += 8) {
            unsigned v[8];
#pragma unroll
            for (int k = 0; k < 8; ++k) {
                int j = __shfl(idx, i + k);
                v[k] = *(const unsigned*)&hs[(size_t)j * HID + c];
            }
#pragma unroll
            for (int k = 0; k < 8; ++k) {
                float f[4]; fp8x4_to_f32(v[k], f);
                a0 += f[0]; a1 += f[1]; a2 += f[2]; a3 += f[3];
            }
        }
        for (; i + 4 <= nb; i += 4) {
            unsigned v[4];
#pragma unroll
            for (int k = 0; k < 4; ++k) {
                int j = __shfl(idx, i + k);
                v[k] = *(const unsigned*)&hs[(size_t)j * HID + c];
            }
#pragma unroll
            for (int k = 0; k < 4; ++k) {
                float f[4]; fp8x4_to_f32(v[k], f);
                a0 += f[0]; a1 += f[1]; a2 += f[2]; a3 += f[3];
            }
        }
        for (; i < nb; ++i) {
            int j = __shfl(idx, i);
            unsigned u = *(const unsigned*)&hs[(size_t)j * HID + c];
            float f[4]; fp8x4_to_f32(u, f);
            a0 += f[0]; a1 += f[1]; a2 += f[2]; a3 += f[3];
        }
    }
    float dv = dinv[node];
    uchar4 r;
    r.x = f32_to_fp8(dv * a0); r.y = f32_to_fp8(dv * a1);
    r.z = f32_to_fp8(dv * a2); r.w = f32_to_fp8(dv * a3);
    *(uchar4*)&out[(size_t)node * HID + c] = r;
}

// ---------------- aggregation, 128 channels, fp8 gather (UNscaled xs8), fp8 output --------
// a = dinv[node]*x[node] + sum_s dinv[s]*x[s]; out = fp8(dinv[node] * a)

__global__ __launch_bounds__(256) void k_agg128(const unsigned char* __restrict__ xs,
                                                const int* __restrict__ csr,
                                                const int* __restrict__ offs,
                                                const int* __restrict__ deg,
                                                const float* __restrict__ dinv,
                                                unsigned char* __restrict__ out, int n) {
    int wid = threadIdx.x >> 6, lane = threadIdx.x & 63;
    int node = blockIdx.x * 4 + wid;
    if (node >= n) return;
    int half = lane >> 5, l32 = lane & 31;
    int c = l32 << 2;
    float dvn = dinv[node];
    float a0 = 0.f, a1 = 0.f, a2 = 0.f, a3 = 0.f;
    if (half == 0) {
        unsigned u = *(const unsigned*)&xs[(size_t)node * DIN + c];
        float f[4]; fp8x4_to_f32(u, f);
        a0 = dvn * f[0]; a1 = dvn * f[1]; a2 = dvn * f[2]; a3 = dvn * f[3];
    }
    int s0 = offs[node], cnt = deg[node];
    for (int base = 0; base < cnt; base += 64) {
        int nb = min(64, cnt - base);
        int idx = (lane < nb) ? __builtin_nontemporal_load(&csr[s0 + base + lane]) : 0;
        int i = 0;
        for (; i + 8 <= nb; i += 8) {
            unsigned v[4]; float dvj[4];
#pragma unroll
            for (int k = 0; k < 4; ++k) {
                int j = __shfl(idx, i + 2 * k + half);
                v[k] = *(const unsigned*)&xs[(size_t)j * DIN + c];
                dvj[k] = dinv[j];
            }
#pragma unroll
            for (int k = 0; k < 4; ++k) {
                float f[4]; fp8x4_to_f32(v[k], f);
                a0 = fmaf(dvj[k], f[0], a0); a1 = fmaf(dvj[k], f[1], a1);
                a2 = fmaf(dvj[k], f[2], a2); a3 = fmaf(dvj[k], f[3], a3);
            }
        }
        for (; i < nb; i += 2) {
            int e = i + half;
            int j = __shfl(idx, e < nb ? e : 0);
            if (e < nb) {
                unsigned u = *(const unsigned*)&xs[(size_t)j * DIN + c];
                float dvj = dinv[j];
                float f[4]; fp8x4_to_f32(u, f);
                a0 = fmaf(dvj, f[0], a0); a1 = fmaf(dvj, f[1], a1);
                a2 = fmaf(dvj, f[2], a2); a3 = fmaf(dvj, f[3], a3);
            }
        }
    }
    a0 += __shfl_xor(a0, 32);
    a1 += __shfl_xor(a1, 32);
    a2 += __shfl_xor(a2, 32);
    a3 += __shfl_xor(a3, 32);
    if (half == 0) {
        uchar4 r;
        r.x = f32_to_fp8(dvn * a0); r.y = f32_to_fp8(dvn * a1);
        r.z = f32_to_fp8(dvn * a2); r.w = f32_to_fp8(dvn * a3);
        *(uchar4*)&out[(size_t)node * DIN + c] = r;
    }
}

// ---------------- head MLP with fused pooled-reduction from scratch ----------------

__global__ __launch_bounds__(256) void k_mlp(const float* __restrict__ scratch,
                                             const int* __restrict__ batch,
                                             const float* __restrict__ countsf,
                                             const float* __restrict__ Wf1,
                                             const float* __restrict__ bf1,
                                             const float* __restrict__ Wf2,
                                             const float* __restrict__ bf2,
                                             float* __restrict__ out) {
    __shared__ float p[HID];
    __shared__ float z[HID];
    int g = blockIdx.x, t = threadIdx.x;
    int lo = 0, hi = NN;
    while (lo < hi) { int mid = (lo + hi) >> 1; if (batch[mid] < g) lo = mid + 1; else hi = mid; }
    int s = lo;
    lo = s; hi = NN;
    while (lo < hi) { int mid = (lo + hi) >> 1; if (batch[mid] <= g) lo = mid + 1; else hi = mid; }
    int e = lo;
    float sum = 0.f;
    if (e > s) {
        int bx0 = s >> 7, bx1 = (e - 1) >> 7;
        for (int bx = bx0; bx <= bx1; ++bx) {
            int gl = min(g - batch[bx << 7], 3);
            sum += scratch[(size_t)bx * 1024 + gl * 256 + t];
        }
    }
    float cnt = fmaxf(countsf[g], 1.0f);
    p[t] = sum / cnt;
    __syncthreads();
    float accz = bf1[t];
    for (int k = 0; k < HID; ++k)
        accz = fmaf(p[k], Wf1[k * HID + t], accz);
    z[t] = fmaxf(accz, 0.f);
    __syncthreads();
    if (t < NCLS) {
        float o = bf2[t];
        for (int k = 0; k < HID; ++k)
            o = fmaf(z[k], Wf2[k * NCLS + t], o);
        float sp = fmaxf(o, 0.f) + log1pf(expf(-fabsf(o)));
        out[g * NCLS + t] = sp + 0.001f;
    }
}

// ---------------- launch ----------------

extern "C" void kernel_launch(void* const* d_in, const int* in_sizes, int n_in,
                              void* d_out, int out_size, void* d_ws, size_t ws_size,
                              hipStream_t stream) {
    const float* x     = (const float*)d_in[0];
    const int*   ei    = (const int*)d_in[1];
    const int*   batch = (const int*)d_in[2];
    const float* W1    = (const float*)d_in[3];
    const float* b1    = (const float*)d_in[4];
    const float* W2    = (const float*)d_in[5];
    const float* b2    = (const float*)d_in[6];
    const float* Wf1   = (const float*)d_in[7];
    const float* bf1   = (const float*)d_in[8];
    const float* Wf2   = (const float*)d_in[9];
    const float* bf2   = (const float*)d_in[10];
    float* out = (float*)d_out;

    const int* srcv = ei;
    const int* dstv = ei + NE;

    char* p = (char*)d_ws;
    auto take = [&](size_t bytes) -> char* {
        char* q = p; p += (bytes + 255) & ~(size_t)255; return q;
    };
    // big0 (51.2MB): [xs8 fp8 12.8MB][xa8 fp8 12.8MB] early; r8 fp8 [NN][256] later
    char* big0 = take((size_t)NN * HID * 2);
    // big1 (51.2MB): pairs u32 (6.4MB) early; h8 fp8 (25.6MB) + scratch (3.2MB) later
    char* big1 = take((size_t)NN * HID * 2);
    unsigned char*  xs8 = (unsigned char*)big0;                            // [NN][128] fp8 (UNscaled)
    unsigned char*  xa8 = (unsigned char*)(big0 + (size_t)NN * DIN);       // [NN][128] fp8
    unsigned char*  h8  = (unsigned char*)big1;                            // [NN][256] fp8
    unsigned char*  r8  = (unsigned char*)big0;                            // [NN][256] fp8 (xs8/xa8 dead)
    float* scratch = (float*)(big1 + (size_t)NN * HID);                    // [NBR][4][256] f32
    unsigned* pairs = (unsigned*)big1;                                     // dead before h8
    unsigned short* wt1  = (unsigned short*)take((size_t)DIN * HID * 2);
    unsigned short* wt2  = (unsigned short*)take((size_t)HID * HID * 2);
    int*   histg   = (int*)take((size_t)NHIST * 4);
    int*   bsum    = (int*)take(64 * 4);
    int*   boff    = (int*)take(64 * 4);
    int*   deg     = (int*)take((size_t)NN * 4);
    int*   offs    = (int*)take((size_t)NN * 4);
    int*   csr     = (int*)take((size_t)NE * 4);
    float* dinv    = (float*)take((size_t)NN * 4);
    float* countsf = (float*)take((size_t)NG * 4);

    // hist + all casts in one launch (cast blocks run concurrently with hist blocks)
    k_hist<<<NBLK + CAST_BLKS, 256, 0, stream>>>(dstv, histg, x, xs8, W1, wt1, W2, wt2);
    k_bsum2<<<64, 256, 0, stream>>>(histg, bsum);
    k_scanb2<<<1, 64, 0, stream>>>(bsum, boff, batch, countsf);
    k_offs2<<<64, 256, 0, stream>>>(histg, boff);
    k_scatter<<<NBLK, 256, 0, stream>>>(srcv, dstv, histg, pairs);
    k_csr<<<NBUK, 256, 0, stream>>>(pairs, histg, csr, deg, dinv, offs);

    // layer 1: fp8 gather (dinv deferred) -> xa8, GEMM1 (writes h8 fp8)
    k_agg128<<<(NN + 3) / 4, 256, 0, stream>>>(xs8, csr, offs, deg, dinv, xa8, NN);
    k_gemm_mfma<1><<<NBR, 512, 0, stream>>>(xa8, wt1, dinv, b1, (void*)h8, batch, NN, DIN);
    // layer 2: fp8 gather -> r8, GEMM2 (psum -> scratch)
    k_agg256<<<(NN + 3) / 4, 256, 0, stream>>>(h8, csr, offs, deg, dinv, r8, NN);
    k_gemm_mfma<2><<<NBR, 512, 0, stream>>>(r8, wt2, dinv, b2, (void*)scratch, batch, NN, HID);

    // head: fused reduce + MLP
    k_mlp<<<NG, 256, 0, stream>>>(scratch, batch, countsf, Wf1, bf1, Wf2, bf2, out);
}

// Round 24
// 309.732 us; speedup vs baseline: 1.2553x; 1.0019x over previous
//
#include <hip/hip_runtime.h>
#include <math.h>

#define NN   100000
#define NE   1600000
#define DIN  128
#define HID  256
#define NG   64
#define NCLS 10

// counting-sort CSR build parameters
#define NBLK 128          // edge-chunk blocks (NE/NBLK = 12500 exactly)
#define EPB  (NE / NBLK)
#define NBUK 512          // dst buckets
#define NPB  196          // nodes per bucket (512*196 = 100352 >= NN)
#define NHIST (NBUK * NBLK)   // 65536 = 64 chunks x 1024
#define NBR  ((NN + 127) / 128)   // 782 row-blocks in the GEMM grid

#define XQ (NN * 32)                        // x quads
#define CAST_TOTAL (XQ + (DIN + HID) * HID) // cast work items
#define CAST_BLKS  ((CAST_TOTAL + 255) / 256)

using bf16x8 = __attribute__((ext_vector_type(8))) short;
using f32x4  = __attribute__((ext_vector_type(4))) float;
using f32x2  = __attribute__((ext_vector_type(2))) float;
using u32x2  = __attribute__((ext_vector_type(2))) unsigned int;
using u32x4  = __attribute__((ext_vector_type(4))) unsigned int;

static __device__ __forceinline__ unsigned short f2bf(float f) {
    unsigned u = __float_as_uint(f);
    u += 0x7fff + ((u >> 16) & 1);   // round-to-nearest-even
    return (unsigned short)(u >> 16);
}

// ---- OCP fp8 e4m3 helpers ----
static __device__ __forceinline__ unsigned char f32_to_fp8(float f) {
    float a = fminf(fabsf(f), 448.f);
    unsigned bits = __float_as_uint(a * 0x1p-120f);
    bits += 0x7ffff + ((bits >> 20) & 1);
    unsigned e4 = (bits >> 20) & 0x7f;
    return (unsigned char)(e4 | (f < 0.f ? 0x80u : 0u));
}
#if __has_builtin(__builtin_amdgcn_cvt_pk_f32_fp8)
#define HAVE_CVT_FP8 1
#endif
static __device__ __forceinline__ void fp8x4_to_f32(unsigned u, float* f) {
#ifdef HAVE_CVT_FP8
    f32x2 lo = __builtin_amdgcn_cvt_pk_f32_fp8((int)u, false);
    f32x2 hi = __builtin_amdgcn_cvt_pk_f32_fp8((int)u, true);
    f[0] = lo[0]; f[1] = lo[1]; f[2] = hi[0]; f[3] = hi[1];
#else
#pragma unroll
    for (int k = 0; k < 4; ++k) {
        unsigned b = (u >> (8 * k)) & 0xffu;
        unsigned bits = ((b & 0x80u) << 24) | ((b & 0x7fu) << 20);
        f[k] = __uint_as_float(bits) * 0x1p+120f;
    }
#endif
}
// 8 fp8 -> 8 bf16 packed (exact: e4m3 values are bf16-representable)
static __device__ __forceinline__ int4 fp8x8_to_bf16x8(unsigned lo, unsigned hi) {
    float f[8];
    fp8x4_to_f32(lo, f);
    fp8x4_to_f32(hi, f + 4);
    int4 r;
    r.x = (int)((__float_as_uint(f[0]) >> 16) | (__float_as_uint(f[1]) & 0xffff0000u));
    r.y = (int)((__float_as_uint(f[2]) >> 16) | (__float_as_uint(f[3]) & 0xffff0000u));
    r.z = (int)((__float_as_uint(f[4]) >> 16) | (__float_as_uint(f[5]) & 0xffff0000u));
    r.w = (int)((__float_as_uint(f[6]) >> 16) | (__float_as_uint(f[7]) & 0xffff0000u));
    return r;
}

// ---------------- k_hist + merged casts ----------------
// blocks [0, NBLK): per-(block,bucket) dst histogram
// blocks [NBLK, NBLK+CAST_BLKS): xs8 = fp8(x) (UNscaled; dinv deferred to agg128),
//                                wt1/wt2 = bf16 weight transposes

__global__ __launch_bounds__(256) void k_hist(const int* __restrict__ dst,
                                              int* __restrict__ histg,
                                              const float* __restrict__ x,
                                              unsigned char* __restrict__ xs8,
                                              const float* __restrict__ W1,
                                              unsigned short* __restrict__ Wt1,
                                              const float* __restrict__ W2,
                                              unsigned short* __restrict__ Wt2) {
    const int t = threadIdx.x;
    if (blockIdx.x >= NBLK) {
        int i = (blockIdx.x - NBLK) * 256 + t;
        if (i < XQ) {
            int nd = i >> 5;
            int q  = i & 31;
            const float4 v = *(const float4*)&x[(size_t)nd * DIN + q * 4];
            uchar4 o;
            o.x = f32_to_fp8(v.x); o.y = f32_to_fp8(v.y);
            o.z = f32_to_fp8(v.z); o.w = f32_to_fp8(v.w);
            *(uchar4*)&xs8[(size_t)nd * DIN + q * 4] = o;
        } else {
            int j = i - XQ;
            if (j < DIN * HID) {
                int k = j >> 8, nc = j & 255;
                Wt1[nc * DIN + k] = f2bf(W1[j]);
            } else if (j < (DIN + HID) * HID) {
                int jj = j - DIN * HID;
                int k = jj >> 8, nc = jj & 255;
                Wt2[nc * HID + k] = f2bf(W2[jj]);
            }
        }
        return;
    }
    __shared__ int h[NBUK];
    for (int i = t; i < NBUK; i += 256) h[i] = 0;
    __syncthreads();
    const int e0 = blockIdx.x * EPB, e1 = e0 + EPB;
    for (int e = e0 + t; e < e1; e += 256)
        atomicAdd(&h[(unsigned)__builtin_nontemporal_load(&dst[e]) / NPB], 1);
    __syncthreads();
    for (int i = t; i < NBUK; i += 256)
        histg[i * NBLK + blockIdx.x] = h[i];
}

__global__ __launch_bounds__(256) void k_bsum2(const int* __restrict__ d,
                                               int* __restrict__ bsum) {
    __shared__ int sd[256];
    int t = threadIdx.x;
    const int4 v = *(const int4*)&d[blockIdx.x * 1024 + t * 4];
    sd[t] = v.x + v.y + v.z + v.w;
    __syncthreads();
    for (int off = 128; off > 0; off >>= 1) {
        if (t < off) sd[t] += sd[t + off];
        __syncthreads();
    }
    if (t == 0) bsum[blockIdx.x] = sd[0];
}

__global__ void k_scanb2(const int* __restrict__ bsum, int* __restrict__ boff,
                         const int* __restrict__ batch, float* __restrict__ countsf) {
    __shared__ int tmp[64];
    int t = threadIdx.x;
    int v = bsum[t];
    tmp[t] = v; __syncthreads();
    for (int off = 1; off < 64; off <<= 1) {
        int u = (t >= off) ? tmp[t - off] : 0;
        __syncthreads();
        tmp[t] += u;
        __syncthreads();
    }
    boff[t] = tmp[t] - v;
    int g = t;
    int lo = 0, hi = NN;
    while (lo < hi) { int mid = (lo + hi) >> 1; if (batch[mid] < g) lo = mid + 1; else hi = mid; }
    int lb = lo;
    lo = 0; hi = NN;
    while (lo < hi) { int mid = (lo + hi) >> 1; if (batch[mid] <= g) lo = mid + 1; else hi = mid; }
    countsf[g] = (float)(lo - lb);
}

__global__ __launch_bounds__(256) void k_offs2(int* __restrict__ d,
                                               const int* __restrict__ boff) {
    __shared__ int ts[256];
    int t = threadIdx.x;
    int base = blockIdx.x * 1024 + t * 4;
    int4 v = *(const int4*)&d[base];
    int s = v.x + v.y + v.z + v.w;
    ts[t] = s; __syncthreads();
    for (int off = 1; off < 256; off <<= 1) {
        int u = (t >= off) ? ts[t - off] : 0;
        __syncthreads();
        ts[t] += u;
        __syncthreads();
    }
    int run = ts[t] - s + boff[blockIdx.x];
    int4 o;
    o.x = run; run += v.x;
    o.y = run; run += v.y;
    o.z = run; run += v.z;
    o.w = run; run += v.w;
    *(int4*)&d[base] = o;
}

__global__ __launch_bounds__(256) void k_scatter(const int* __restrict__ src,
                                                 const int* __restrict__ dst,
                                                 const int* __restrict__ offg,
                                                 unsigned* __restrict__ pairs) {
    __shared__ int cur[NBUK];
    const int t = threadIdx.x;
    for (int i = t; i < NBUK; i += 256) cur[i] = offg[i * NBLK + blockIdx.x];
    __syncthreads();
    const int e0 = blockIdx.x * EPB, e1 = e0 + EPB;
    for (int e = e0 + t; e < e1; e += 256) {
        int d = __builtin_nontemporal_load(&dst[e]);
        int sv = __builtin_nontemporal_load(&src[e]);
        int b = (unsigned)d / NPB;
        int li = d - b * NPB;
        unsigned pk = ((unsigned)li << 24) | (unsigned)sv;
        int p = atomicAdd(&cur[b], 1);
        __builtin_nontemporal_store(pk, &pairs[p]);
    }
}

__global__ __launch_bounds__(256) void k_csr(const unsigned* __restrict__ pairs,
                                             const int* __restrict__ offg,
                                             int* __restrict__ csr,
                                             int* __restrict__ deg,
                                             float* __restrict__ dinv,
                                             int* __restrict__ offs) {
    __shared__ int cnt[NPB];
    __shared__ int loff[256];
    __shared__ int cur[NPB];
    const int b = blockIdx.x, t = threadIdx.x;
    const int s     = offg[b * NBLK];
    const int e_end = (b == NBUK - 1) ? NE : offg[(b + 1) * NBLK];
    const int nb0   = b * NPB;
    const int nnod  = min(NPB, NN - nb0);
    if (t < NPB) cnt[t] = 0;
    __syncthreads();
    for (int e = s + t; e < e_end; e += 256)
        atomicAdd(&cnt[pairs[e] >> 24], 1);
    __syncthreads();
    int v = (t < NPB) ? cnt[t] : 0;
    loff[t] = v;
    __syncthreads();
    for (int off = 1; off < 256; off <<= 1) {
        int u = (t >= off) ? loff[t - off] : 0;
        __syncthreads();
        loff[t] += u;
        __syncthreads();
    }
    int myoff = loff[t] - v;
    __syncthreads();
    loff[t] = myoff;
    if (t < NPB) cur[t] = 0;
    __syncthreads();
    if (t < nnod) {
        int node = nb0 + t;
        int dg = cnt[t];
        deg[node]  = dg;
        dinv[node] = rsqrtf((float)(dg + 1));
        offs[node] = s + myoff;
    }
    for (int e = s + t; e < e_end; e += 256) {
        unsigned pk = pairs[e];
        int li = pk >> 24;
        int p = atomicAdd(&cur[li], 1);
        csr[s + loff[li] + p] = (int)(pk & 0xffffffu);
    }
}

// ---------------- MFMA GEMM: 128 rows x 256 cols per block, 8 waves, BK=64 ----------------
// MODE 1: out_fp8[row*HID+col] = e4m3(dinv[row] * relu(acc + bias[col]))
// MODE 2: per-block psum[4][256] -> scratch (no global atomics)

template <int MODE>
__global__ __launch_bounds__(512) void k_gemm_mfma(const unsigned char* __restrict__ A8,
                                                   const unsigned short* __restrict__ Wt,
                                                   const float* __restrict__ dinv,
                                                   const float* __restrict__ bias,
                                                   void* __restrict__ outp,
                                                   const int* __restrict__ batch,
                                                   int M, int K) {
    __shared__ unsigned short As[128 * 72];
    __shared__ unsigned short Bs[256 * 72];
    __shared__ float psum[4][256];
    __shared__ int gloc[128];
    const int t = threadIdx.x;
    const int lane = t & 63;
    const int wid = t >> 6;
    const int wr = wid & 1, wc = wid >> 1;
    const int bm = blockIdx.x * 128;
    const int lr = lane & 15;
    const int ko = (lane >> 4) << 3;

    f32x4 acc[4][4] = {};

    const int arow = t >> 2;
    const int akq  = (t & 3) << 4;
    const int brow = t >> 1;
    const int bkq  = (t & 1) << 5;

    int g0 = 0, gend = 0;
    if (MODE == 2) {
        g0 = batch[bm];
        gend = batch[min(bm + 127, M - 1)];
        for (int i = t; i < 4 * 256; i += 512) ((float*)psum)[i] = 0.f;
        if (t < 128) gloc[t] = (bm + t < M) ? min(batch[bm + t] - g0, 3) : 0;
    }

    for (int kk = 0; kk < K; kk += 64) {
        {
            int row = bm + arow;
            u32x4 v; v.x = v.y = v.z = v.w = 0u;
            if (row < M) v = *(const u32x4*)&A8[(size_t)row * K + kk + akq];
            *(int4*)&As[arow * 72 + akq]     = fp8x8_to_bf16x8(v.x, v.y);
            *(int4*)&As[arow * 72 + akq + 8] = fp8x8_to_bf16x8(v.z, v.w);
        }
        {
            const unsigned short* wsrc = &Wt[(size_t)brow * K + kk + bkq];
#pragma unroll
            for (int q = 0; q < 4; ++q)
                *(int4*)&Bs[brow * 72 + bkq + q * 8] = *(const int4*)&wsrc[q * 8];
        }
        __syncthreads();
#pragma unroll
        for (int ks = 0; ks < 64; ks += 32) {
            bf16x8 af[4], bfr[4];
#pragma unroll
            for (int mf = 0; mf < 4; ++mf)
                af[mf] = *(const bf16x8*)&As[(wr * 64 + mf * 16 + lr) * 72 + ks + ko];
#pragma unroll
            for (int nf = 0; nf < 4; ++nf)
                bfr[nf] = *(const bf16x8*)&Bs[(wc * 64 + nf * 16 + lr) * 72 + ks + ko];
#pragma unroll
            for (int mf = 0; mf < 4; ++mf)
#pragma unroll
                for (int nf = 0; nf < 4; ++nf)
                    acc[mf][nf] = __builtin_amdgcn_mfma_f32_16x16x32_bf16(af[mf], bfr[nf], acc[mf][nf], 0, 0, 0);
        }
        __syncthreads();
    }

    if (MODE == 1) {
        unsigned char* out8 = (unsigned char*)outp;
#pragma unroll
        for (int mf = 0; mf < 4; ++mf) {
#pragma unroll
            for (int b = 0; b < 4; ++b) {
                int row = bm + wr * 64 + mf * 16 + (lane >> 4) * 4 + b;
                if (row >= M) continue;
                float dv = dinv[row];
#pragma unroll
                for (int nf = 0; nf < 4; ++nf) {
                    int col = wc * 64 + nf * 16 + lr;
                    float v = fmaxf(acc[mf][nf][b] + bias[col], 0.f);
                    out8[(size_t)row * HID + col] = f32_to_fp8(dv * v);
                }
            }
        }
    } else {
        const int q4 = (lane >> 4) << 2;
        if (gend == g0) {
#pragma unroll
            for (int nf = 0; nf < 4; ++nf) {
                const int lcol = wc * 64 + nf * 16 + lr;
                const float bb = bias[lcol];
                float rsum = 0.f;
#pragma unroll
                for (int mf = 0; mf < 4; ++mf)
#pragma unroll
                    for (int b = 0; b < 4; ++b) {
                        int lrow = wr * 64 + mf * 16 + q4 + b;
                        if (bm + lrow < M) rsum += fmaxf(acc[mf][nf][b] + bb, 0.f);
                    }
                rsum += __shfl_xor(rsum, 16);
                rsum += __shfl_xor(rsum, 32);
                if ((lane >> 4) == 0) atomicAdd(&psum[0][lcol], rsum);
            }
        } else {
#pragma unroll
            for (int nf = 0; nf < 4; ++nf) {
                const int lcol = wc * 64 + nf * 16 + lr;
                const float bb = bias[lcol];
                float run = 0.f; int gcur = 0;
#pragma unroll
                for (int mf = 0; mf < 4; ++mf) {
#pragma unroll
                    for (int b = 0; b < 4; ++b) {
                        int lrow = wr * 64 + mf * 16 + q4 + b;
                        if (bm + lrow < M) {
                            int gl = gloc[lrow];
                            float v = fmaxf(acc[mf][nf][b] + bb, 0.f);
                            if (gl != gcur) {
                                if (run != 0.f) atomicAdd(&psum[gcur][lcol], run);
                                run = 0.f; gcur = gl;
                            }
                            run += v;
                        }
                    }
                }
                if (run != 0.f) atomicAdd(&psum[gcur][lcol], run);
            }
        }
        __syncthreads();
        float* scratch = (float*)outp;
        size_t base = (size_t)blockIdx.x * 1024;
        for (int i = t; i < 1024; i += 512)
            __builtin_nontemporal_store(((const float*)psum)[i], &scratch[base + i]);
    }
}

// ---------------- aggregation, 256 channels, fp8 gather, fp8 output ----------------

__global__ __launch_bounds__(256) void k_agg256(const unsigned char* __restrict__ hs,
                                                const int* __restrict__ csr,
                                                const int* __restrict__ offs,
                                                const int* __restrict__ deg,
                                                const float* __restrict__ dinv,
                                                unsigned char* __restrict__ out, int n) {
    int wid = threadIdx.x >> 6, lane = threadIdx.x & 63;
    int node = blockIdx.x * 4 + wid;
    if (node >= n) return;
    int c = lane << 2;
    float a0, a1, a2, a3;
    {
        unsigned u = *(const unsigned*)&hs[(size_t)node * HID + c];
        float f[4]; fp8x4_to_f32(u, f);
        a0 = f[0]; a1 = f[1]; a2 = f[2]; a3 = f[3];
    }
    int s0 = offs[node], cnt = deg[node];
    for (int base = 0; base < cnt; base += 64) {
        int nb = min(64, cnt - base);
        int idx = (lane < nb) ? __builtin_nontemporal_load(&csr[s0 + base + lane]) : 0;
        int i = 0;
        for (; i + 8 <= nb; i += 8) {
            unsigned v[8];
#pragma unroll
            for (int k = 0; k < 8; ++k) {
                int j = __shfl(idx, i + k);
                v[k] = *(const unsigned*)&hs[(size_t)j * HID + c];
            }
#pragma unroll
            for (int k = 0; k < 8; ++k) {
                float f[4]; fp8x4_to_f32(v[k], f);
                a0 += f[0]; a1 += f[1]; a2 += f[2]; a3 += f[3];
            }
        }
        for (; i + 4 <= nb; i += 4) {
            unsigned v[4];
#pragma unroll
            for (int k = 0; k < 4; ++k) {
                int j = __shfl(idx, i + k);
                v[k] = *(const unsigned*)&hs[(size_t)j * HID + c];
            }
#pragma unroll
            for (int k = 0; k < 4; ++k) {
                float f[4]; fp8x4_to_f32(v[k], f);
                a0 += f[0]; a1 += f[1]; a2 += f[2]; a3 += f[3];
            }
        }
        for (; i < nb; ++i) {
            int j = __shfl(idx, i);
            unsigned u = *(const unsigned*)&hs[(size_t)j * HID + c];
            float f[4]; fp8x4_to_f32(u, f);
            a0 += f[0]; a1 += f[1]; a2 += f[2]; a3 += f[3];
        }
    }
    float dv = dinv[node];
    uchar4 r;
    r.x = f32_to_fp8(dv * a0); r.y = f32_to_fp8(dv * a1);
    r.z = f32_to_fp8(dv * a2); r.w = f32_to_fp8(dv * a3);
    *(uchar4*)&out[(size_t)node * HID + c] = r;
}

// ---------------- aggregation, 128 channels, fp8 gather (UNscaled xs8), fp8 output --------
// a = dinv[node]*x[node] + sum_s dinv[s]*x[s]; out = fp8(dinv[node] * a)

__global__ __launch_bounds__(256) void k_agg128(const unsigned char* __restrict__ xs,
                                                const int* __restrict__ csr,
                                                const int* __restrict__ offs,
                                                const int* __restrict__ deg,
                                                const float* __restrict__ dinv,
                                                unsigned char* __restrict__ out, int n) {
    int wid = threadIdx.x >> 6, lane = threadIdx.x & 63;
    int node = blockIdx.x * 4 + wid;
    if (node >= n) return;
    int half = lane >> 5, l32 = lane & 31;
    int c = l32 << 2;
    float dvn = dinv[node];
    float a0 = 0.f, a1 = 0.f, a2 = 0.f, a3 = 0.f;
    if (half == 0) {
        unsigned u = *(const unsigned*)&xs[(size_t)node * DIN + c];
        float f[4]; fp8x4_to_f32(u, f);
        a0 = dvn * f[0]; a1 = dvn * f[1]; a2 = dvn * f[2]; a3 = dvn * f[3];
    }
    int s0 = offs[node], cnt = deg[node];
    for (int base = 0; base < cnt; base += 64) {
        int nb = min(64, cnt - base);
        int idx = (lane < nb) ? __builtin_nontemporal_load(&csr[s0 + base + lane]) : 0;
        int i = 0;
        for (; i + 8 <= nb; i += 8) {
            unsigned v[4]; float dvj[4];
#pragma unroll
            for (int k = 0; k < 4; ++k) {
                int j = __shfl(idx, i + 2 * k + half);
                v[k] = *(const unsigned*)&xs[(size_t)j * DIN + c];
                dvj[k] = dinv[j];
            }
#pragma unroll
            for (int k = 0; k < 4; ++k) {
                float f[4]; fp8x4_to_f32(v[k], f);
                a0 = fmaf(dvj[k], f[0], a0); a1 = fmaf(dvj[k], f[1], a1);
                a2 = fmaf(dvj[k], f[2], a2); a3 = fmaf(dvj[k], f[3], a3);
            }
        }
        for (; i < nb; i += 2) {
            int e = i + half;
            int j = __shfl(idx, e < nb ? e : 0);
            if (e < nb) {
                unsigned u = *(const unsigned*)&xs[(size_t)j * DIN + c];
                float dvj = dinv[j];
                float f[4]; fp8x4_to_f32(u, f);
                a0 = fmaf(dvj, f[0], a0); a1 = fmaf(dvj, f[1], a1);
                a2 = fmaf(dvj, f[2], a2); a3 = fmaf(dvj, f[3], a3);
            }
        }
    }
    a0 += __shfl_xor(a0, 32);
    a1 += __shfl_xor(a1, 32);
    a2 += __shfl_xor(a2, 32);
    a3 += __shfl_xor(a3, 32);
    if (half == 0) {
        uchar4 r;
        r.x = f32_to_fp8(dvn * a0); r.y = f32_to_fp8(dvn * a1);
        r.z = f32_to_fp8(dvn * a2); r.w = f32_to_fp8(dvn * a3);
        *(uchar4*)&out[(size_t)node * DIN + c] = r;
    }
}

// ---------------- head MLP with fused pooled-reduction from scratch ----------------

__global__ __launch_bounds__(256) void k_mlp(const float* __restrict__ scratch,
                                             const int* __restrict__ batch,
                                             const float* __restrict__ countsf,
                                             const float* __restrict__ Wf1,
                                             const float* __restrict__ bf1,
                                             const float* __restrict__ Wf2,
                                             const float* __restrict__ bf2,
                                             float* __restrict__ out) {
    __shared__ float p[HID];
    __shared__ float z[HID];
    int g = blockIdx.x, t = threadIdx.x;
    int lo = 0, hi = NN;
    while (lo < hi) { int mid = (lo + hi) >> 1; if (batch[mid] < g) lo = mid + 1; else hi = mid; }
    int s = lo;
    lo = s; hi = NN;
    while (lo < hi) { int mid = (lo + hi) >> 1; if (batch[mid] <= g) lo = mid + 1; else hi = mid; }
    int e = lo;
    float sum = 0.f;
    if (e > s) {
        int bx0 = s >> 7, bx1 = (e - 1) >> 7;
        for (int bx = bx0; bx <= bx1; ++bx) {
            int gl = min(g - batch[bx << 7], 3);
            sum += scratch[(size_t)bx * 1024 + gl * 256 + t];
        }
    }
    float cnt = fmaxf(countsf[g], 1.0f);
    p[t] = sum / cnt;
    __syncthreads();
    float accz = bf1[t];
    for (int k = 0; k < HID; ++k)
        accz = fmaf(p[k], Wf1[k * HID + t], accz);
    z[t] = fmaxf(accz, 0.f);
    __syncthreads();
    if (t < NCLS) {
        float o = bf2[t];
        for (int k = 0; k < HID; ++k)
            o = fmaf(z[k], Wf2[k * NCLS + t], o);
        float sp = fmaxf(o, 0.f) + log1pf(expf(-fabsf(o)));
        out[g * NCLS + t] = sp + 0.001f;
    }
}

// ---------------- launch ----------------

extern "C" void kernel_launch(void* const* d_in, const int* in_sizes, int n_in,
                              void* d_out, int out_size, void* d_ws, size_t ws_size,
                              hipStream_t stream) {
    const float* x     = (const float*)d_in[0];
    const int*   ei    = (const int*)d_in[1];
    const int*   batch = (const int*)d_in[2];
    const float* W1    = (const float*)d_in[3];
    const float* b1    = (const float*)d_in[4];
    const float* W2    = (const float*)d_in[5];
    const float* b2    = (const float*)d_in[6];
    const float* Wf1   = (const float*)d_in[7];
    const float* bf1   = (const float*)d_in[8];
    const float* Wf2   = (const float*)d_in[9];
    const float* bf2   = (const float*)d_in[10];
    float* out = (float*)d_out;

    const int* srcv = ei;
    const int* dstv = ei + NE;

    char* p = (char*)d_ws;
    auto take = [&](size_t bytes) -> char* {
        char* q = p; p += (bytes + 255) & ~(size_t)255; return q;
    };
    // big0 (51.2MB): [xs8 fp8 12.8MB][xa8 fp8 12.8MB] early; r8 fp8 [NN][256] later
    char* big0 = take((size_t)NN * HID * 2);
    // big1 (51.2MB): pairs u32 (6.4MB) early; h8 fp8 (25.6MB) + scratch (3.2MB) later
    char* big1 = take((size_t)NN * HID * 2);
    unsigned char*  xs8 = (unsigned char*)big0;                            // [NN][128] fp8 (UNscaled)
    unsigned char*  xa8 = (unsigned char*)(big0 + (size_t)NN * DIN);       // [NN][128] fp8
    unsigned char*  h8  = (unsigned char*)big1;                            // [NN][256] fp8
    unsigned char*  r8  = (unsigned char*)big0;                            // [NN][256] fp8 (xs8/xa8 dead)
    float* scratch = (float*)(big1 + (size_t)NN * HID);                    // [NBR][4][256] f32
    unsigned* pairs = (unsigned*)big1;                                     // dead before h8
    unsigned short* wt1  = (unsigned short*)take((size_t)DIN * HID * 2);
    unsigned short* wt2  = (unsigned short*)take((size_t)HID * HID * 2);
    int*   histg   = (int*)take((size_t)NHIST * 4);
    int*   bsum    = (int*)take(64 * 4);
    int*   boff    = (int*)take(64 * 4);
    int*   deg     = (int*)take((size_t)NN * 4);
    int*   offs    = (int*)take((size_t)NN * 4);
    int*   csr     = (int*)take((size_t)NE * 4);
    float* dinv    = (float*)take((size_t)NN * 4);
    float* countsf = (float*)take((size_t)NG * 4);

    // hist + all casts in one launch (cast blocks run concurrently with hist blocks)
    k_hist<<<NBLK + CAST_BLKS, 256, 0, stream>>>(dstv, histg, x, xs8, W1, wt1, W2, wt2);
    k_bsum2<<<64, 256, 0, stream>>>(histg, bsum);
    k_scanb2<<<1, 64, 0, stream>>>(bsum, boff, batch, countsf);
    k_offs2<<<64, 256, 0, stream>>>(histg, boff);
    k_scatter<<<NBLK, 256, 0, stream>>>(srcv, dstv, histg, pairs);
    k_csr<<<NBUK, 256, 0, stream>>>(pairs, histg, csr, deg, dinv, offs);

    // layer 1: fp8 gather (dinv deferred) -> xa8, GEMM1 (writes h8 fp8)
    k_agg128<<<(NN + 3) / 4, 256, 0, stream>>>(xs8, csr, offs, deg, dinv, xa8, NN);
    k_gemm_mfma<1><<<NBR, 512, 0, stream>>>(xa8, wt1, dinv, b1, (void*)h8, batch, NN, DIN);
    // layer 2: fp8 gather -> r8, GEMM2 (psum -> scratch)
    k_agg256<<<(NN + 3) / 4, 256, 0, stream>>>(h8, csr, offs, deg, dinv, r8, NN);
    k_gemm_mfma<2><<<NBR, 512, 0, stream>>>(r8, wt2, dinv, b2, (void*)scratch, batch, NN, HID);

    // head: fused reduce + MLP
    k_mlp<<<NG, 256, 0, stream>>>(scratch, batch, countsf, Wf1, bf1, Wf2, bf2, out);
}